// Round 3
// baseline (21964.598 us; speedup 1.0000x reference)
//
#include <hip/hip_runtime.h>
#include <cstdint>
#include <cstddef>

// ---------------------------------------------------------------------------
// E2E AttDot + 2-layer LSTM decoder + CE loss, bf16 MFMA implementation.
// B=32, T=400, E=D=1024, V=5000, L=100 (101 steps). Loss = mean(CE)*100.
// R3: whole scan in ONE persistent cooperative kernel (grid barriers replace
// 303 launches); pre_enc half-cached in LDS (survives L2 invalidations).
// ---------------------------------------------------------------------------

using short8  = __attribute__((ext_vector_type(8))) short;
using floatx4 = __attribute__((ext_vector_type(4))) float;

#define DEV __device__ __forceinline__

DEV float bf2f(unsigned int h) { union { unsigned int u; float f; } v; v.u = h << 16; return v.f; }
DEV unsigned short f2bf(float f) {
    union { float f; unsigned int u; } v; v.f = f;
    return (unsigned short)((v.u + 0x7fffu + ((v.u >> 16) & 1u)) >> 16);
}
DEV float sigm(float x) { return 1.0f / (1.0f + __expf(-x)); }

// ---------------------------------------------------------------- utilities
__global__ __launch_bounds__(256) void k_zero(unsigned int* p, int n) {
    int i = blockIdx.x * 256 + threadIdx.x;
    if (i < n) p[i] = 0u;
}

__global__ __launch_bounds__(256) void k_conv4(const float* __restrict__ in,
                                               unsigned short* __restrict__ out, int n4) {
    int i = blockIdx.x * 256 + threadIdx.x;
    if (i >= n4) return;
    float4 v = ((const float4*)in)[i];
    unsigned int w0 = (unsigned int)f2bf(v.x) | ((unsigned int)f2bf(v.y) << 16);
    unsigned int w1 = (unsigned int)f2bf(v.z) | ((unsigned int)f2bf(v.w) << 16);
    ((uint2*)(void*)out)[i] = make_uint2(w0, w1);
}

__global__ __launch_bounds__(256) void k_cat2(const float* __restrict__ A, const float* __restrict__ Bsrc,
                                              unsigned short* __restrict__ dst, int N, int Ka, int Kb) {
    int idx = blockIdx.x * 256 + threadIdx.x;
    int K = Ka + Kb;
    if (idx >= N * K) return;
    int n = idx / K, k = idx - n * K;
    float v = (k < Ka) ? A[(size_t)n * Ka + k] : Bsrc[(size_t)n * Kb + (k - Ka)];
    dst[idx] = f2bf(v);
}

__global__ __launch_bounds__(256) void k_woutpad(const float* __restrict__ W, unsigned short* __restrict__ dst) {
    int idx = blockIdx.x * 256 + threadIdx.x;
    if (idx >= 5120 * 2048) return;
    int n = idx >> 11, k = idx & 2047;
    dst[idx] = (n < 5000) ? f2bf(W[(size_t)n * 2048 + k]) : (unsigned short)0;
}

__global__ __launch_bounds__(256) void k_bsum(const float* a0, const float* b0, const float* a1, const float* b1,
                                              float* s0, float* s1) {
    int i = blockIdx.x * 256 + threadIdx.x;
    if (i < 4096) s0[i] = a0[i] + b0[i];
    else if (i < 8192) s1[i - 4096] = a1[i - 4096] + b1[i - 4096];
}

// eys[l][b][d] = bf16(embed[ys_in[b][l]][d])
__global__ __launch_bounds__(256) void k_eys(const float* __restrict__ embed, const int* __restrict__ ys_pad,
                                             unsigned short* __restrict__ eys) {
    int idx = blockIdx.x * 256 + threadIdx.x;
    if (idx >= 3232 * 1024) return;
    int rb = idx >> 10, d = idx & 1023;
    int l = rb >> 5, b = rb & 31;
    int tok = (l == 0) ? 4999 : ys_pad[b * 100 + (l - 1)];
    eys[idx] = f2bf(embed[(size_t)tok * 1024 + d]);
}

// --------------------------------------------------- big 128x128 MFMA GEMM
__global__ __launch_bounds__(256) void k_gemm128(
    const unsigned short* __restrict__ A, const unsigned short* __restrict__ B,
    int K, int N, const float* __restrict__ bias,
    unsigned short* __restrict__ obf, float* __restrict__ of32, int mode) {
    __shared__ uint4 Ab[512];
    __shared__ uint4 Bb[512];
    const int tid = threadIdx.x;
    const int lane = tid & 63, wave = tid >> 6;
    const int r = lane & 15, q = lane >> 4;
    const int wm = wave >> 1, wn = wave & 1;
    const size_t am0 = (size_t)blockIdx.y * 128;
    const size_t bn0 = (size_t)blockIdx.x * 128;
    floatx4 zf = {0.f, 0.f, 0.f, 0.f};
    floatx4 acc[4][4];
#pragma unroll
    for (int i = 0; i < 4; i++)
#pragma unroll
        for (int j = 0; j < 4; j++) acc[i][j] = zf;

    for (int k0 = 0; k0 < K; k0 += 32) {
        __syncthreads();
#pragma unroll
        for (int i = 0; i < 2; ++i) {
            int idx = i * 256 + tid;
            int qq = idx & 3, rr = idx >> 2;
            int slot = (rr >> 4) * 64 + ((qq << 4) | (rr & 15));
            Ab[slot] = *(const uint4*)(const void*)(A + (am0 + rr) * K + k0 + qq * 8);
            Bb[slot] = *(const uint4*)(const void*)(B + (bn0 + rr) * K + k0 + qq * 8);
        }
        __syncthreads();
        short8 af[4], bf[4];
#pragma unroll
        for (int t = 0; t < 4; t++) af[t] = *(const short8*)(const void*)&Ab[(wm * 4 + t) * 64 + lane];
#pragma unroll
        for (int t = 0; t < 4; t++) bf[t] = *(const short8*)(const void*)&Bb[(wn * 4 + t) * 64 + lane];
#pragma unroll
        for (int tm = 0; tm < 4; tm++)
#pragma unroll
            for (int tn = 0; tn < 4; tn++)
                acc[tm][tn] = __builtin_amdgcn_mfma_f32_16x16x32_bf16(af[tm], bf[tn], acc[tm][tn], 0, 0, 0);
    }
#pragma unroll
    for (int tm = 0; tm < 4; tm++) {
#pragma unroll
        for (int tn = 0; tn < 4; tn++) {
            int col = (int)bn0 + wn * 64 + tn * 16 + r;
#pragma unroll
            for (int reg = 0; reg < 4; ++reg) {
                size_t row = am0 + wm * 64 + tm * 16 + q * 4 + reg;
                float v = acc[tm][tn][reg];
                if (mode == 0) {
                    v = tanhf(v + bias[col]);
                    obf[row * (size_t)N + col] = f2bf(v);
                } else {
                    of32[row * (size_t)N + col] = v;
                }
            }
        }
    }
}

// ------------------------------------------------------------ dq (32x1024)
__global__ __launch_bounds__(256) void k_dq(const unsigned short* __restrict__ Wdec,
                                            const unsigned short* __restrict__ z0, int apitch,
                                            const float* __restrict__ bdec,
                                            unsigned short* __restrict__ dq) {
    const int tid = threadIdx.x, lane = tid & 63, wave = tid >> 6;
    if (wave >= 2) return;
    const int r = lane & 15, q = lane >> 4, mt = wave, dcq = blockIdx.x;
    floatx4 acc = {0.f, 0.f, 0.f, 0.f};
    const unsigned short* Brow = Wdec + (size_t)(dcq * 16 + r) * 1024 + q * 8;
    const unsigned short* Arow = z0 + (size_t)(mt * 16 + r) * apitch + q * 8;
#pragma unroll 4
    for (int k0 = 0; k0 < 1024; k0 += 32) {
        short8 bfr = *(const short8*)(const void*)(Brow + k0);
        short8 afr = *(const short8*)(const void*)(Arow + k0);
        acc = __builtin_amdgcn_mfma_f32_16x16x32_bf16(afr, bfr, acc, 0, 0, 0);
    }
    const int n = dcq * 16 + r;
#pragma unroll
    for (int reg = 0; reg < 4; ++reg) {
        int m = mt * 16 + q * 4 + reg;
        dq[m * 1024 + n] = f2bf(tanhf(acc[reg] + bdec[n]));
    }
}

// ------------------------------------------------- persistent scan kernel
struct SArgs {
    const unsigned short* pre;
    const unsigned short* hs;
    const unsigned short* eys;
    const unsigned short* wc0;
    const unsigned short* wc1;
    const unsigned short* wdec;
    unsigned short* dq;
    unsigned short* x0r;
    unsigned short* x1r;
    unsigned short* zall;
    const float* bdec;
    const float* bs0;
    const float* bs1;
    float* c0;
    float* c1;
    float* gp;
    float* part;
    float* lmaxg;
    float* lsumg;
    int* cntA;
    int* cnt0;
    int* cnt1;
    int* gcnt;
    int* gflag;
    const int* hlens;
};

DEV void gbar(int* gcnt, int* gflag, int ep) {
    __syncthreads();
    if (threadIdx.x == 0) {
        __threadfence();
        int old = atomicAdd(gcnt, 1);
        if (old == ep * 256 - 1) {
            __hip_atomic_store(gflag, ep, __ATOMIC_RELAXED, __HIP_MEMORY_SCOPE_AGENT);
        } else {
            while (__hip_atomic_load(gflag, __ATOMIC_RELAXED, __HIP_MEMORY_SCOPE_AGENT) < ep)
                __builtin_amdgcn_s_sleep(2);
        }
        __threadfence();
    }
    __syncthreads();
}

__global__ __launch_bounds__(256, 1) void k_scan(SArgs a) {
    const int blk = blockIdx.x, tid = threadIdx.x;
    const int lane = tid & 63, wave = tid >> 6;
    const int b = blk >> 3, ch = blk & 7;       // attention role
    const int dc = blk >> 2, kc = blk & 3;      // cell role
    const int r = lane & 15, q = lane >> 4;
    const int hlen = a.hlens[b];

    __shared__ __align__(16) unsigned short preS[25 * 1024];  // 50 KB: rows 0..24 of slice
    __shared__ float e4[50][4];
    __shared__ float es[52];
    __shared__ float ps[52];
    __shared__ int lastf;

    // one-time LDS fill: pre[b][ch*50 .. ch*50+24][:]
    {
        const uint4* src = (const uint4*)(const void*)(a.pre + ((size_t)(b * 400 + ch * 50)) * 1024);
        uint4* dst = (uint4*)(void*)preS;
        for (int i = tid; i < 3200; i += 256) dst[i] = src[i];
    }
    __syncthreads();

    int ep = 0;
    for (int l = 0; l < 101; ++l) {
        unsigned short* X0l = a.x0r + (size_t)(l & 1) * 32 * 3072;
        unsigned short* X0n = a.x0r + (size_t)((l + 1) & 1) * 32 * 3072;
        unsigned short* X1l = a.x1r + (size_t)(l & 1) * 32 * 2048;
        unsigned short* X1n = a.x1r + (size_t)((l + 1) & 1) * 32 * 2048;

        // ================= phase A: attention =================
        {
            float dqf[16];
            {
                const uint4* dp = (const uint4*)(const void*)(a.dq + b * 1024 + lane * 16);
                uint4 w0 = dp[0], w1 = dp[1];
                dqf[0] = bf2f(w0.x & 0xffffu); dqf[1] = bf2f(w0.x >> 16);
                dqf[2] = bf2f(w0.y & 0xffffu); dqf[3] = bf2f(w0.y >> 16);
                dqf[4] = bf2f(w0.z & 0xffffu); dqf[5] = bf2f(w0.z >> 16);
                dqf[6] = bf2f(w0.w & 0xffffu); dqf[7] = bf2f(w0.w >> 16);
                dqf[8]  = bf2f(w1.x & 0xffffu); dqf[9]  = bf2f(w1.x >> 16);
                dqf[10] = bf2f(w1.y & 0xffffu); dqf[11] = bf2f(w1.y >> 16);
                dqf[12] = bf2f(w1.z & 0xffffu); dqf[13] = bf2f(w1.z >> 16);
                dqf[14] = bf2f(w1.w & 0xffffu); dqf[15] = bf2f(w1.w >> 16);
            }
            const unsigned short* preg = a.pre + ((size_t)(b * 400 + ch * 50)) * 1024 + lane * 16;
            for (int tl = wave; tl < 50; tl += 4) {
                uint4 v0, v1;
                if (tl < 25) {
                    const uint4* p = (const uint4*)(const void*)(preS + tl * 1024 + lane * 16);
                    v0 = p[0]; v1 = p[1];
                } else {
                    const uint4* p = (const uint4*)(const void*)(preg + (size_t)tl * 1024);
                    v0 = p[0]; v1 = p[1];
                }
                float s = 0.f;
                s += bf2f(v0.x & 0xffffu) * dqf[0] + bf2f(v0.x >> 16) * dqf[1];
                s += bf2f(v0.y & 0xffffu) * dqf[2] + bf2f(v0.y >> 16) * dqf[3];
                s += bf2f(v0.z & 0xffffu) * dqf[4] + bf2f(v0.z >> 16) * dqf[5];
                s += bf2f(v0.w & 0xffffu) * dqf[6] + bf2f(v0.w >> 16) * dqf[7];
                s += bf2f(v1.x & 0xffffu) * dqf[8]  + bf2f(v1.x >> 16) * dqf[9];
                s += bf2f(v1.y & 0xffffu) * dqf[10] + bf2f(v1.y >> 16) * dqf[11];
                s += bf2f(v1.z & 0xffffu) * dqf[12] + bf2f(v1.z >> 16) * dqf[13];
                s += bf2f(v1.w & 0xffffu) * dqf[14] + bf2f(v1.w >> 16) * dqf[15];
                s += __shfl_xor(s, 1, 64);
                s += __shfl_xor(s, 2, 64);
                s += __shfl_xor(s, 4, 64);
                s += __shfl_xor(s, 8, 64);
                if ((lane & 15) == 0) e4[tl][lane >> 4] = s;
            }
            __syncthreads();
            if (tid < 50) {
                float4 v = *(const float4*)(const void*)e4[tid];
                float e = v.x + v.y + v.z + v.w;
                int t = ch * 50 + tid;
                es[tid] = (t < hlen) ? 2.0f * e : -1e30f;
            }
            __syncthreads();
            float lmax = -1e30f;
#pragma unroll
            for (int i = 0; i < 50; ++i) lmax = fmaxf(lmax, es[i]);
            if (tid < 50) ps[tid] = (es[tid] > -5e29f) ? __expf(es[tid] - lmax) : 0.f;
            __syncthreads();
            if (tid == 0) {
                float ssum = 0.f;
                for (int i = 0; i < 50; ++i) ssum += ps[i];
                a.lmaxg[b * 8 + ch] = lmax;
                a.lsumg[b * 8 + ch] = ssum;
            }
            const int c = tid * 4;
            float a0 = 0.f, a1 = 0.f, a2 = 0.f, a3 = 0.f;
            const unsigned short* hsb = a.hs + ((size_t)(b * 400 + ch * 50)) * 1024 + c;
            for (int tl = 0; tl < 50; ++tl) {
                float p = ps[tl];
                uint2 h = *(const uint2*)(const void*)(hsb + (size_t)tl * 1024);
                a0 += p * bf2f(h.x & 0xffffu); a1 += p * bf2f(h.x >> 16);
                a2 += p * bf2f(h.y & 0xffffu); a3 += p * bf2f(h.y >> 16);
            }
            *(float4*)(void*)(a.part + ((size_t)(b * 8 + ch)) * 1024 + c) = make_float4(a0, a1, a2, a3);
            __threadfence();
            __syncthreads();
            if (tid == 0) lastf = (atomicAdd(a.cntA + b, 1) == 8 * l + 7);
            __syncthreads();
            if (lastf) {
                __threadfence();
                float lm[8], ls[8];
#pragma unroll
                for (int i = 0; i < 8; ++i) { lm[i] = a.lmaxg[b * 8 + i]; ls[i] = a.lsumg[b * 8 + i]; }
                float gm = -1e30f;
#pragma unroll
                for (int i = 0; i < 8; ++i) gm = fmaxf(gm, lm[i]);
                float Zs = 0.f;
#pragma unroll
                for (int i = 0; i < 8; ++i) Zs += ls[i] * __expf(lm[i] - gm);
                const float inv = 1.0f / Zs;
                float o0 = 0.f, o1 = 0.f, o2 = 0.f, o3 = 0.f;
#pragma unroll
                for (int i = 0; i < 8; ++i) {
                    float coef = __expf(lm[i] - gm) * inv;
                    float4 q4 = *(const float4*)(const void*)(a.part + ((size_t)(b * 8 + i)) * 1024 + c);
                    o0 += coef * q4.x; o1 += coef * q4.y; o2 += coef * q4.z; o3 += coef * q4.w;
                }
                uint2 attp;
                attp.x = (unsigned int)f2bf(o0) | ((unsigned int)f2bf(o1) << 16);
                attp.y = (unsigned int)f2bf(o2) | ((unsigned int)f2bf(o3) << 16);
                *(uint2*)(void*)(X0l + (size_t)b * 3072 + 1024 + c) = attp;
                *(uint2*)(void*)(a.zall + ((size_t)(l * 32 + b)) * 2048 + 1024 + c) = attp;
                uint2 ey = *(const uint2*)(const void*)(a.eys + (size_t)l * 32 * 1024 + b * 1024 + c);
                *(uint2*)(void*)(X0l + (size_t)b * 3072 + c) = ey;
            }
        }
        gbar(a.gcnt, a.gflag, ++ep);

        // ================= phase B: LSTM cell 0 =================
        {
            const unsigned short* Br = a.wc0 + ((size_t)(wave * 1024 + dc * 16 + r)) * 3072 + kc * 768 + q * 8;
            const unsigned short* A0 = X0l + (size_t)r * 3072 + kc * 768 + q * 8;
            const unsigned short* A1 = A0 + 16 * 3072;
            floatx4 acc0 = {0.f, 0.f, 0.f, 0.f}, acc1 = acc0;
#pragma unroll 4
            for (int kk = 0; kk < 768; kk += 32) {
                short8 bfr = *(const short8*)(const void*)(Br + kk);
                short8 a0  = *(const short8*)(const void*)(A0 + kk);
                short8 a1  = *(const short8*)(const void*)(A1 + kk);
                acc0 = __builtin_amdgcn_mfma_f32_16x16x32_bf16(a0, bfr, acc0, 0, 0, 0);
                acc1 = __builtin_amdgcn_mfma_f32_16x16x32_bf16(a1, bfr, acc1, 0, 0, 0);
            }
            const int n = wave * 1024 + dc * 16 + r;
            float* gb = a.gp + ((size_t)kc * 4096 + n) * 32;
            *(floatx4*)(void*)(gb + q * 4) = acc0;
            *(floatx4*)(void*)(gb + 16 + q * 4) = acc1;
            __threadfence();
            __syncthreads();
            if (tid == 0) lastf = (atomicAdd(a.cnt0 + dc, 1) == 4 * l + 3);
            __syncthreads();
            if (lastf) {
                __threadfence();
                for (int idx = tid; idx < 512; idx += 256) {
                    const int bb = idx & 31, dl = idx >> 5;
                    const int d = dc * 16 + dl;
                    float gg[4];
#pragma unroll
                    for (int gate = 0; gate < 4; ++gate) {
                        float s = a.bs0[gate * 1024 + d];
#pragma unroll
                        for (int kcc = 0; kcc < 4; ++kcc)
                            s += a.gp[((size_t)kcc * 4096 + gate * 1024 + d) * 32 + bb];
                        gg[gate] = s;
                    }
                    const float cn = sigm(gg[1]) * a.c0[d * 32 + bb] + sigm(gg[0]) * tanhf(gg[2]);
                    a.c0[d * 32 + bb] = cn;
                    const unsigned short hb = f2bf(sigm(gg[3]) * tanhf(cn));
                    X1l[bb * 2048 + d] = hb;            // z0_l for cell1/dq
                    X0n[(size_t)bb * 3072 + 2048 + d] = hb;  // z0old for next step's cell0
                }
            }
        }
        gbar(a.gcnt, a.gflag, ++ep);

        // ================= phase C: LSTM cell 1 + next dq =================
        {
            const unsigned short* Br = a.wc1 + ((size_t)(wave * 1024 + dc * 16 + r)) * 2048 + kc * 512 + q * 8;
            const unsigned short* A0 = X1l + (size_t)r * 2048 + kc * 512 + q * 8;
            const unsigned short* A1 = A0 + 16 * 2048;
            floatx4 acc0 = {0.f, 0.f, 0.f, 0.f}, acc1 = acc0;
#pragma unroll 4
            for (int kk = 0; kk < 512; kk += 32) {
                short8 bfr = *(const short8*)(const void*)(Br + kk);
                short8 a0  = *(const short8*)(const void*)(A0 + kk);
                short8 a1  = *(const short8*)(const void*)(A1 + kk);
                acc0 = __builtin_amdgcn_mfma_f32_16x16x32_bf16(a0, bfr, acc0, 0, 0, 0);
                acc1 = __builtin_amdgcn_mfma_f32_16x16x32_bf16(a1, bfr, acc1, 0, 0, 0);
            }
            const int n = wave * 1024 + dc * 16 + r;
            float* gb = a.gp + ((size_t)kc * 4096 + n) * 32;
            *(floatx4*)(void*)(gb + q * 4) = acc0;
            *(floatx4*)(void*)(gb + 16 + q * 4) = acc1;
            __threadfence();
            __syncthreads();
            if (tid == 0) lastf = (atomicAdd(a.cnt1 + dc, 1) == 4 * l + 3);
            __syncthreads();
            // next-step dq on kc==0 blocks (z0_l ready since phase B)
            if (kc == 0 && wave < 2) {
                floatx4 acc = {0.f, 0.f, 0.f, 0.f};
                const unsigned short* Brow = a.wdec + (size_t)(dc * 16 + r) * 1024 + q * 8;
                const unsigned short* Arow = X1l + (size_t)(wave * 16 + r) * 2048 + q * 8;
#pragma unroll 4
                for (int k0 = 0; k0 < 1024; k0 += 32) {
                    short8 bfr = *(const short8*)(const void*)(Brow + k0);
                    short8 afr = *(const short8*)(const void*)(Arow + k0);
                    acc = __builtin_amdgcn_mfma_f32_16x16x32_bf16(afr, bfr, acc, 0, 0, 0);
                }
                const int nn = dc * 16 + r;
#pragma unroll
                for (int reg = 0; reg < 4; ++reg) {
                    int m = wave * 16 + q * 4 + reg;
                    a.dq[m * 1024 + nn] = f2bf(tanhf(acc[reg] + a.bdec[nn]));
                }
            }
            if (lastf) {
                __threadfence();
                for (int idx = tid; idx < 512; idx += 256) {
                    const int bb = idx & 31, dl = idx >> 5;
                    const int d = dc * 16 + dl;
                    float gg[4];
#pragma unroll
                    for (int gate = 0; gate < 4; ++gate) {
                        float s = a.bs1[gate * 1024 + d];
#pragma unroll
                        for (int kcc = 0; kcc < 4; ++kcc)
                            s += a.gp[((size_t)kcc * 4096 + gate * 1024 + d) * 32 + bb];
                        gg[gate] = s;
                    }
                    const float cn = sigm(gg[1]) * a.c1[d * 32 + bb] + sigm(gg[0]) * tanhf(gg[2]);
                    a.c1[d * 32 + bb] = cn;
                    const unsigned short hb = f2bf(sigm(gg[3]) * tanhf(cn));
                    X1n[bb * 2048 + 1024 + d] = hb;     // z1old for next step
                    a.zall[((size_t)(l * 32 + bb)) * 2048 + d] = hb;
                }
            }
        }
        gbar(a.gcnt, a.gflag, ++ep);
    }
}

// ----------------------------------------------------------- CE reduction
__global__ __launch_bounds__(256) void k_ce(const float* __restrict__ y, const float* __restrict__ bout,
                                            const int* __restrict__ ys_pad, float* __restrict__ out) {
    const int rrow = blockIdx.x;
    const int l = rrow >> 5, b = rrow & 31;
    const float* yp = y + (size_t)rrow * 5120;
    const int tid = threadIdx.x;
    __shared__ float red[256];
    float m = -1e30f;
    for (int c = tid; c < 5000; c += 256) m = fmaxf(m, yp[c] + bout[c]);
    red[tid] = m; __syncthreads();
    for (int s = 128; s; s >>= 1) { if (tid < s) red[tid] = fmaxf(red[tid], red[tid + s]); __syncthreads(); }
    const float gmax = red[0]; __syncthreads();
    float ss = 0.f;
    for (int c = tid; c < 5000; c += 256) ss += __expf(yp[c] + bout[c] - gmax);
    red[tid] = ss; __syncthreads();
    for (int s = 128; s; s >>= 1) { if (tid < s) red[tid] += red[tid + s]; __syncthreads(); }
    if (tid == 0) {
        const int tgt = (l < 100) ? ys_pad[b * 100 + l] : 4999;
        const float lt = yp[tgt] + bout[tgt];
        const float ce = logf(red[0]) + gmax - lt;
        atomicAdd(out, ce * (100.0f / 3232.0f));
    }
}

// ---------------------------------------------------------------------------
extern "C" void kernel_launch(void* const* d_in, const int* in_sizes, int n_in,
                              void* d_out, int out_size, void* d_ws, size_t ws_size,
                              hipStream_t stream) {
    const float* hs_pad = (const float*)d_in[0];
    const float* embed  = (const float*)d_in[1];
    const float* Wenc   = (const float*)d_in[2];
    const float* benc   = (const float*)d_in[3];
    const float* Wdec   = (const float*)d_in[4];
    const float* bdec   = (const float*)d_in[5];
    const float* W_ih0  = (const float*)d_in[6];
    const float* W_hh0  = (const float*)d_in[7];
    const float* b_ih0  = (const float*)d_in[8];
    const float* b_hh0  = (const float*)d_in[9];
    const float* W_ih1  = (const float*)d_in[10];
    const float* W_hh1  = (const float*)d_in[11];
    const float* b_ih1  = (const float*)d_in[12];
    const float* b_hh1  = (const float*)d_in[13];
    const float* Wout   = (const float*)d_in[14];
    const float* bout   = (const float*)d_in[15];
    const int*   hlens  = (const int*)d_in[16];
    const int*   ys_pad = (const int*)d_in[17];
    float* out = (float*)d_out;
    uint8_t* ws = (uint8_t*)d_ws;

    constexpr size_t OFF_HS   = 0;                       // 26,214,400
    constexpr size_t OFF_PRE  = OFF_HS   + 26214400;     // 26,214,400
    constexpr size_t OFF_WC0  = OFF_PRE  + 26214400;     // 25,165,824
    constexpr size_t OFF_WC1  = OFF_WC0  + 25165824;     // 16,777,216
    constexpr size_t OFF_WOUT = OFF_WC1  + 16777216;     // 20,971,520
    constexpr size_t OFF_WENC = OFF_WOUT + 20971520;     // 2,097,152
    constexpr size_t OFF_WDEC = OFF_WENC + 2097152;      // 2,097,152
    constexpr size_t OFF_EYS  = OFF_WDEC + 2097152;      // 6,619,136
    constexpr size_t OFF_ZALL = OFF_EYS  + 6619136;      // 13,631,488
    constexpr size_t OFF_GP   = OFF_ZALL + 13631488;     // 2,097,152
    constexpr size_t OFF_PART = OFF_GP   + 2097152;      // 1,048,576
    constexpr size_t OFF_LMAX = OFF_PART + 1048576;      // 1,024
    constexpr size_t OFF_LSUM = OFF_LMAX + 1024;         // 1,024
    constexpr size_t OFF_DQ   = OFF_LSUM + 1024;         // 65,536
    constexpr size_t OFF_X0R  = OFF_DQ   + 65536;        // 393,216
    constexpr size_t OFF_X1R  = OFF_X0R  + 393216;       // 262,144
    constexpr size_t OFF_C0   = OFF_X1R  + 262144;       // 131,072
    constexpr size_t OFF_C1   = OFF_C0   + 131072;       // 131,072
    constexpr size_t OFF_BS0  = OFF_C1   + 131072;       // 16,384
    constexpr size_t OFF_BS1  = OFF_BS0  + 16384;        // 16,384
    constexpr size_t OFF_CNT  = OFF_BS1  + 16384;        // 768
    constexpr size_t OFF_Y    = 0;

    unsigned short* HS   = (unsigned short*)(ws + OFF_HS);
    unsigned short* PRE  = (unsigned short*)(ws + OFF_PRE);
    unsigned short* WC0  = (unsigned short*)(ws + OFF_WC0);
    unsigned short* WC1  = (unsigned short*)(ws + OFF_WC1);
    unsigned short* WOUTP= (unsigned short*)(ws + OFF_WOUT);
    unsigned short* WENC = (unsigned short*)(ws + OFF_WENC);
    unsigned short* WDEC = (unsigned short*)(ws + OFF_WDEC);
    unsigned short* EYS  = (unsigned short*)(ws + OFF_EYS);
    unsigned short* ZALL = (unsigned short*)(ws + OFF_ZALL);
    float* GP    = (float*)(ws + OFF_GP);
    float* PART  = (float*)(ws + OFF_PART);
    float* LMAX  = (float*)(ws + OFF_LMAX);
    float* LSUM  = (float*)(ws + OFF_LSUM);
    unsigned short* DQ  = (unsigned short*)(ws + OFF_DQ);
    unsigned short* X0R = (unsigned short*)(ws + OFF_X0R);
    unsigned short* X1R = (unsigned short*)(ws + OFF_X1R);
    float* C0   = (float*)(ws + OFF_C0);
    float* C1   = (float*)(ws + OFF_C1);
    float* BS0  = (float*)(ws + OFF_BS0);
    float* BS1  = (float*)(ws + OFF_BS1);
    int* CNT    = (int*)(ws + OFF_CNT);      // [0..31] A, [32..95] B, [96..159] C, [160] gcnt, [161] gflag
    float* Y = (float*)(ws + OFF_Y);

    auto Zr = [&](void* p, int n_u32) {
        k_zero<<<dim3((n_u32 + 255) / 256), dim3(256), 0, stream>>>((unsigned int*)p, n_u32);
    };

    // ---- setup (re-done every call)
    Zr(X0R, 98304);
    Zr(X1R, 65536);
    Zr(C0, 32768);  Zr(C1, 32768);
    Zr(CNT, 192);
    Zr(d_out, 1);
    Zr(ZALL + (size_t)3232 * 2048, 98304);

    k_conv4<<<dim3(12800), dim3(256), 0, stream>>>(hs_pad, HS, 3276800);
    k_conv4<<<dim3(1024),  dim3(256), 0, stream>>>(Wenc, WENC, 262144);
    k_conv4<<<dim3(1024),  dim3(256), 0, stream>>>(Wdec, WDEC, 262144);
    k_cat2<<<dim3(49152), dim3(256), 0, stream>>>(W_ih0, W_hh0, WC0, 4096, 2048, 1024);
    k_cat2<<<dim3(32768), dim3(256), 0, stream>>>(W_ih1, W_hh1, WC1, 4096, 1024, 1024);
    k_woutpad<<<dim3(40960), dim3(256), 0, stream>>>(Wout, WOUTP);
    k_bsum<<<dim3(32), dim3(256), 0, stream>>>(b_ih0, b_hh0, b_ih1, b_hh1, BS0, BS1);
    k_eys<<<dim3(12928), dim3(256), 0, stream>>>(embed, ys_pad, EYS);

    k_gemm128<<<dim3(8, 100), dim3(256), 0, stream>>>(HS, WENC, 1024, 1024, benc, PRE, (float*)nullptr, 0);
    k_dq<<<dim3(64), dim3(256), 0, stream>>>(WDEC, X1R, 2048, bdec, DQ);

    // ---- the scan: one persistent cooperative kernel
    SArgs sa;
    sa.pre = PRE;  sa.hs = HS;  sa.eys = EYS;
    sa.wc0 = WC0;  sa.wc1 = WC1; sa.wdec = WDEC;
    sa.dq = DQ;    sa.x0r = X0R; sa.x1r = X1R; sa.zall = ZALL;
    sa.bdec = bdec; sa.bs0 = BS0; sa.bs1 = BS1;
    sa.c0 = C0;    sa.c1 = C1;  sa.gp = GP;
    sa.part = PART; sa.lmaxg = LMAX; sa.lsumg = LSUM;
    sa.cntA = CNT; sa.cnt0 = CNT + 32; sa.cnt1 = CNT + 96;
    sa.gcnt = CNT + 160; sa.gflag = CNT + 161;
    sa.hlens = hlens;
    void* kp[] = { &sa };
    hipLaunchCooperativeKernel((const void*)k_scan, dim3(256), dim3(256), kp, 0, stream);

    // ---- output projection + CE
    k_gemm128<<<dim3(40, 26), dim3(256), 0, stream>>>(ZALL, WOUTP, 2048, 5120, (const float*)nullptr,
                                                      (unsigned short*)nullptr, Y, 1);
    k_ce<<<dim3(3232), dim3(256), 0, stream>>>(Y, bout, ys_pad, out);
}

// Round 4
// 8043.629 us; speedup vs baseline: 2.7307x; 2.7307x over previous
//
#include <hip/hip_runtime.h>
#include <cstdint>
#include <cstddef>

// ---------------------------------------------------------------------------
// E2E AttDot + 2-layer LSTM decoder + CE loss, bf16 MFMA implementation.
// B=32, T=400, E=D=1024, V=5000, L=100 (101 steps). Loss = mean(CE)*100.
// R4: persistent cooperative scan with ZERO device fences in the hot loop.
// All cross-block traffic via relaxed agent-scope atomics (sc1 per-access
// coherence); release = s_waitcnt(0) + relaxed arrival add. Weights stay
// L2-resident (no buffer_inv/wbl2 ever executed inside the loop).
// ---------------------------------------------------------------------------

using short8  = __attribute__((ext_vector_type(8))) short;
using floatx4 = __attribute__((ext_vector_type(4))) float;
typedef unsigned long long u64;

#define DEV __device__ __forceinline__

DEV float bf2f(unsigned int h) { union { unsigned int u; float f; } v; v.u = h << 16; return v.f; }
DEV unsigned short f2bf(float f) {
    union { float f; unsigned int u; } v; v.f = f;
    return (unsigned short)((v.u + 0x7fffu + ((v.u >> 16) & 1u)) >> 16);
}
DEV float sigm(float x) { return 1.0f / (1.0f + __expf(-x)); }

// relaxed agent-scope (coherent-point) accessors: compile to sc1 loads/stores,
// no cache-wide invalidate/writeback.
DEV u64  lda64(const void* p) { return __hip_atomic_load((const u64*)p, __ATOMIC_RELAXED, __HIP_MEMORY_SCOPE_AGENT); }
DEV void sta64(void* p, u64 v) { __hip_atomic_store((u64*)p, v, __ATOMIC_RELAXED, __HIP_MEMORY_SCOPE_AGENT); }
DEV void sta32(void* p, unsigned int v) { __hip_atomic_store((unsigned int*)p, v, __ATOMIC_RELAXED, __HIP_MEMORY_SCOPE_AGENT); }
DEV float ldaf(const void* p) { return __hip_atomic_load((const float*)p, __ATOMIC_RELAXED, __HIP_MEMORY_SCOPE_AGENT); }
DEV void staf(void* p, float v) { __hip_atomic_store((float*)p, v, __ATOMIC_RELAXED, __HIP_MEMORY_SCOPE_AGENT); }
DEV int  arrive(int* p) { return __hip_atomic_fetch_add(p, 1, __ATOMIC_RELAXED, __HIP_MEMORY_SCOPE_AGENT); }
DEV short8 lda_s8(const void* p) {
    union { u64 q[2]; short8 s; } u;
    u.q[0] = lda64(p);
    u.q[1] = lda64((const char*)p + 8);
    return u.s;
}

// ---------------------------------------------------------------- utilities
__global__ __launch_bounds__(256) void k_zero(unsigned int* p, int n) {
    int i = blockIdx.x * 256 + threadIdx.x;
    if (i < n) p[i] = 0u;
}

__global__ __launch_bounds__(256) void k_conv4(const float* __restrict__ in,
                                               unsigned short* __restrict__ out, int n4) {
    int i = blockIdx.x * 256 + threadIdx.x;
    if (i >= n4) return;
    float4 v = ((const float4*)in)[i];
    unsigned int w0 = (unsigned int)f2bf(v.x) | ((unsigned int)f2bf(v.y) << 16);
    unsigned int w1 = (unsigned int)f2bf(v.z) | ((unsigned int)f2bf(v.w) << 16);
    ((uint2*)(void*)out)[i] = make_uint2(w0, w1);
}

__global__ __launch_bounds__(256) void k_cat2(const float* __restrict__ A, const float* __restrict__ Bsrc,
                                              unsigned short* __restrict__ dst, int N, int Ka, int Kb) {
    int idx = blockIdx.x * 256 + threadIdx.x;
    int K = Ka + Kb;
    if (idx >= N * K) return;
    int n = idx / K, k = idx - n * K;
    float v = (k < Ka) ? A[(size_t)n * Ka + k] : Bsrc[(size_t)n * Kb + (k - Ka)];
    dst[idx] = f2bf(v);
}

__global__ __launch_bounds__(256) void k_woutpad(const float* __restrict__ W, unsigned short* __restrict__ dst) {
    int idx = blockIdx.x * 256 + threadIdx.x;
    if (idx >= 5120 * 2048) return;
    int n = idx >> 11, k = idx & 2047;
    dst[idx] = (n < 5000) ? f2bf(W[(size_t)n * 2048 + k]) : (unsigned short)0;
}

__global__ __launch_bounds__(256) void k_bsum(const float* a0, const float* b0, const float* a1, const float* b1,
                                              float* s0, float* s1) {
    int i = blockIdx.x * 256 + threadIdx.x;
    if (i < 4096) s0[i] = a0[i] + b0[i];
    else if (i < 8192) s1[i - 4096] = a1[i - 4096] + b1[i - 4096];
}

// eys[l][b][d] = bf16(embed[ys_in[b][l]][d])
__global__ __launch_bounds__(256) void k_eys(const float* __restrict__ embed, const int* __restrict__ ys_pad,
                                             unsigned short* __restrict__ eys) {
    int idx = blockIdx.x * 256 + threadIdx.x;
    if (idx >= 3232 * 1024) return;
    int rb = idx >> 10, d = idx & 1023;
    int l = rb >> 5, b = rb & 31;
    int tok = (l == 0) ? 4999 : ys_pad[b * 100 + (l - 1)];
    eys[idx] = f2bf(embed[(size_t)tok * 1024 + d]);
}

// --------------------------------------------------- big 128x128 MFMA GEMM
__global__ __launch_bounds__(256) void k_gemm128(
    const unsigned short* __restrict__ A, const unsigned short* __restrict__ B,
    int K, int N, const float* __restrict__ bias,
    unsigned short* __restrict__ obf, float* __restrict__ of32, int mode) {
    __shared__ uint4 Ab[512];
    __shared__ uint4 Bb[512];
    const int tid = threadIdx.x;
    const int lane = tid & 63, wave = tid >> 6;
    const int r = lane & 15, q = lane >> 4;
    const int wm = wave >> 1, wn = wave & 1;
    const size_t am0 = (size_t)blockIdx.y * 128;
    const size_t bn0 = (size_t)blockIdx.x * 128;
    floatx4 zf = {0.f, 0.f, 0.f, 0.f};
    floatx4 acc[4][4];
#pragma unroll
    for (int i = 0; i < 4; i++)
#pragma unroll
        for (int j = 0; j < 4; j++) acc[i][j] = zf;

    for (int k0 = 0; k0 < K; k0 += 32) {
        __syncthreads();
#pragma unroll
        for (int i = 0; i < 2; ++i) {
            int idx = i * 256 + tid;
            int qq = idx & 3, rr = idx >> 2;
            int slot = (rr >> 4) * 64 + ((qq << 4) | (rr & 15));
            Ab[slot] = *(const uint4*)(const void*)(A + (am0 + rr) * K + k0 + qq * 8);
            Bb[slot] = *(const uint4*)(const void*)(B + (bn0 + rr) * K + k0 + qq * 8);
        }
        __syncthreads();
        short8 af[4], bf[4];
#pragma unroll
        for (int t = 0; t < 4; t++) af[t] = *(const short8*)(const void*)&Ab[(wm * 4 + t) * 64 + lane];
#pragma unroll
        for (int t = 0; t < 4; t++) bf[t] = *(const short8*)(const void*)&Bb[(wn * 4 + t) * 64 + lane];
#pragma unroll
        for (int tm = 0; tm < 4; tm++)
#pragma unroll
            for (int tn = 0; tn < 4; tn++)
                acc[tm][tn] = __builtin_amdgcn_mfma_f32_16x16x32_bf16(af[tm], bf[tn], acc[tm][tn], 0, 0, 0);
    }
#pragma unroll
    for (int tm = 0; tm < 4; tm++) {
#pragma unroll
        for (int tn = 0; tn < 4; tn++) {
            int col = (int)bn0 + wn * 64 + tn * 16 + r;
#pragma unroll
            for (int reg = 0; reg < 4; ++reg) {
                size_t row = am0 + wm * 64 + tm * 16 + q * 4 + reg;
                float v = acc[tm][tn][reg];
                if (mode == 0) {
                    v = tanhf(v + bias[col]);
                    obf[row * (size_t)N + col] = f2bf(v);
                } else {
                    of32[row * (size_t)N + col] = v;
                }
            }
        }
    }
}

// ------------------------------------------------------------ dq (32x1024)
__global__ __launch_bounds__(256) void k_dq(const unsigned short* __restrict__ Wdec,
                                            const unsigned short* __restrict__ z0, int apitch,
                                            const float* __restrict__ bdec,
                                            unsigned short* __restrict__ dq) {
    const int tid = threadIdx.x, lane = tid & 63, wave = tid >> 6;
    if (wave >= 2) return;
    const int r = lane & 15, q = lane >> 4, mt = wave, dcq = blockIdx.x;
    floatx4 acc = {0.f, 0.f, 0.f, 0.f};
    const unsigned short* Brow = Wdec + (size_t)(dcq * 16 + r) * 1024 + q * 8;
    const unsigned short* Arow = z0 + (size_t)(mt * 16 + r) * apitch + q * 8;
#pragma unroll 4
    for (int k0 = 0; k0 < 1024; k0 += 32) {
        short8 bfr = *(const short8*)(const void*)(Brow + k0);
        short8 afr = *(const short8*)(const void*)(Arow + k0);
        acc = __builtin_amdgcn_mfma_f32_16x16x32_bf16(afr, bfr, acc, 0, 0, 0);
    }
    const int n = dcq * 16 + r;
#pragma unroll
    for (int reg = 0; reg < 4; ++reg) {
        int m = mt * 16 + q * 4 + reg;
        dq[m * 1024 + n] = f2bf(tanhf(acc[reg] + bdec[n]));
    }
}

// ------------------------------------------------- persistent scan kernel
struct SArgs {
    const unsigned short* pre;
    const unsigned short* hs;
    const unsigned short* eys;
    const unsigned short* wc0;
    const unsigned short* wc1;
    const unsigned short* wdec;
    unsigned short* dq;
    unsigned short* x0r;
    unsigned short* x1r;
    unsigned short* zall;
    const float* bdec;
    const float* bs0;
    const float* bs1;
    float* c0;
    float* c1;
    float* gp;
    float* part;
    float* lmaxg;
    float* lsumg;
    int* cntA;
    int* cnt0;
    int* cnt1;
    int* gcnt;
    int* gflag;
    const int* hlens;
};

// fence-free grid barrier: release via s_waitcnt(0) (all our shared stores are
// write-through agent atomics, acked at the coherent point).
DEV void gbar(int* gcnt, int* gflag, int ep) {
    __builtin_amdgcn_s_waitcnt(0);
    __syncthreads();
    if (threadIdx.x == 0) {
        int old = arrive(gcnt);
        if (old == ep * 256 - 1) {
            __hip_atomic_store(gflag, ep, __ATOMIC_RELAXED, __HIP_MEMORY_SCOPE_AGENT);
        } else {
            while (__hip_atomic_load(gflag, __ATOMIC_RELAXED, __HIP_MEMORY_SCOPE_AGENT) < ep)
                __builtin_amdgcn_s_sleep(1);
        }
    }
    __syncthreads();
}

__global__ __launch_bounds__(256, 1) void k_scan(SArgs a) {
    const int blk = blockIdx.x, tid = threadIdx.x;
    const int lane = tid & 63, wave = tid >> 6;
    const int b = blk >> 3, ch = blk & 7;       // attention role
    const int dc = blk >> 2, kc = blk & 3;      // cell role
    const int r = lane & 15, q = lane >> 4;
    const int hlen = a.hlens[b];

    __shared__ __align__(16) unsigned short preS[25 * 1024];   // 50 KB
    __shared__ __align__(16) unsigned short AS[32 * 776];      // 49.7 KB (A-operand stage)
    __shared__ float dqS[32][16];
    __shared__ float e4[50][4];
    __shared__ float es[52];
    __shared__ float ps[52];
    __shared__ int lastf;

    // one-time LDS fill: pre[b][ch*50 .. ch*50+24][:]  (plain: read-only data)
    {
        const uint4* src = (const uint4*)(const void*)(a.pre + ((size_t)(b * 400 + ch * 50)) * 1024);
        uint4* dst = (uint4*)(void*)preS;
        for (int i = tid; i < 3200; i += 256) dst[i] = src[i];
    }
    __syncthreads();

    int ep = 0;
    for (int l = 0; l < 101; ++l) {
        unsigned short* X0l = a.x0r + (size_t)(l & 1) * 32 * 3072;
        unsigned short* X0n = a.x0r + (size_t)((l + 1) & 1) * 32 * 3072;
        unsigned short* X1l = a.x1r + (size_t)(l & 1) * 32 * 2048;
        unsigned short* X1n = a.x1r + (size_t)((l + 1) & 1) * 32 * 2048;

        // ================= phase A: attention =================
        {
            float dqf[16];
            {
                union { u64 q[4]; unsigned int w[8]; } u;
                const char* dp = (const char*)(a.dq + b * 1024 + lane * 16);
#pragma unroll
                for (int i = 0; i < 4; ++i) u.q[i] = lda64(dp + i * 8);
#pragma unroll
                for (int i = 0; i < 8; ++i) {
                    dqf[2 * i]     = bf2f(u.w[i] & 0xffffu);
                    dqf[2 * i + 1] = bf2f(u.w[i] >> 16);
                }
            }
            const unsigned short* preg = a.pre + ((size_t)(b * 400 + ch * 50)) * 1024 + lane * 16;
            for (int tl = wave; tl < 50; tl += 4) {
                uint4 v0, v1;
                if (tl < 25) {
                    const uint4* p = (const uint4*)(const void*)(preS + tl * 1024 + lane * 16);
                    v0 = p[0]; v1 = p[1];
                } else {
                    const uint4* p = (const uint4*)(const void*)(preg + (size_t)tl * 1024);
                    v0 = p[0]; v1 = p[1];
                }
                float s = 0.f;
                s += bf2f(v0.x & 0xffffu) * dqf[0] + bf2f(v0.x >> 16) * dqf[1];
                s += bf2f(v0.y & 0xffffu) * dqf[2] + bf2f(v0.y >> 16) * dqf[3];
                s += bf2f(v0.z & 0xffffu) * dqf[4] + bf2f(v0.z >> 16) * dqf[5];
                s += bf2f(v0.w & 0xffffu) * dqf[6] + bf2f(v0.w >> 16) * dqf[7];
                s += bf2f(v1.x & 0xffffu) * dqf[8]  + bf2f(v1.x >> 16) * dqf[9];
                s += bf2f(v1.y & 0xffffu) * dqf[10] + bf2f(v1.y >> 16) * dqf[11];
                s += bf2f(v1.z & 0xffffu) * dqf[12] + bf2f(v1.z >> 16) * dqf[13];
                s += bf2f(v1.w & 0xffffu) * dqf[14] + bf2f(v1.w >> 16) * dqf[15];
                s += __shfl_xor(s, 1, 64);
                s += __shfl_xor(s, 2, 64);
                s += __shfl_xor(s, 4, 64);
                s += __shfl_xor(s, 8, 64);
                if ((lane & 15) == 0) e4[tl][lane >> 4] = s;
            }
            __syncthreads();
            if (tid < 50) {
                float4 v = *(const float4*)(const void*)e4[tid];
                float e = v.x + v.y + v.z + v.w;
                int t = ch * 50 + tid;
                es[tid] = (t < hlen) ? 2.0f * e : -1e30f;
            }
            __syncthreads();
            float lmax = -1e30f;
#pragma unroll
            for (int i = 0; i < 50; ++i) lmax = fmaxf(lmax, es[i]);
            if (tid < 50) ps[tid] = (es[tid] > -5e29f) ? __expf(es[tid] - lmax) : 0.f;
            __syncthreads();
            if (tid == 0) {
                float ssum = 0.f;
                for (int i = 0; i < 50; ++i) ssum += ps[i];
                staf(a.lmaxg + b * 8 + ch, lmax);
                staf(a.lsumg + b * 8 + ch, ssum);
            }
            const int c = tid * 4;
            float a0 = 0.f, a1 = 0.f, a2 = 0.f, a3 = 0.f;
            const unsigned short* hsb = a.hs + ((size_t)(b * 400 + ch * 50)) * 1024 + c;
            for (int tl = 0; tl < 50; ++tl) {
                float p = ps[tl];
                uint2 h = *(const uint2*)(const void*)(hsb + (size_t)tl * 1024);
                a0 += p * bf2f(h.x & 0xffffu); a1 += p * bf2f(h.x >> 16);
                a2 += p * bf2f(h.y & 0xffffu); a3 += p * bf2f(h.y >> 16);
            }
            {
                float* pb = a.part + ((size_t)(b * 8 + ch)) * 1024 + c;
                union { float f[2]; u64 q; } p0, p1;
                p0.f[0] = a0; p0.f[1] = a1; p1.f[0] = a2; p1.f[1] = a3;
                sta64(pb, p0.q); sta64(pb + 2, p1.q);
            }
            __builtin_amdgcn_s_waitcnt(0);
            __syncthreads();
            if (tid == 0) lastf = (arrive(a.cntA + b) == 8 * l + 7);
            __syncthreads();
            if (lastf) {
                float lm[8], ls[8];
#pragma unroll
                for (int i = 0; i < 8; ++i) {
                    lm[i] = ldaf(a.lmaxg + b * 8 + i);
                    ls[i] = ldaf(a.lsumg + b * 8 + i);
                }
                float gm = -1e30f;
#pragma unroll
                for (int i = 0; i < 8; ++i) gm = fmaxf(gm, lm[i]);
                float Zs = 0.f;
#pragma unroll
                for (int i = 0; i < 8; ++i) Zs += ls[i] * __expf(lm[i] - gm);
                const float inv = 1.0f / Zs;
                float o0 = 0.f, o1 = 0.f, o2 = 0.f, o3 = 0.f;
#pragma unroll
                for (int i = 0; i < 8; ++i) {
                    float coef = __expf(lm[i] - gm) * inv;
                    const float* qp = a.part + ((size_t)(b * 8 + i)) * 1024 + c;
                    union { u64 q; float f[2]; } u0, u1;
                    u0.q = lda64(qp); u1.q = lda64(qp + 2);
                    o0 += coef * u0.f[0]; o1 += coef * u0.f[1];
                    o2 += coef * u1.f[0]; o3 += coef * u1.f[1];
                }
                union { unsigned int w[2]; u64 q; } ap;
                ap.w[0] = (unsigned int)f2bf(o0) | ((unsigned int)f2bf(o1) << 16);
                ap.w[1] = (unsigned int)f2bf(o2) | ((unsigned int)f2bf(o3) << 16);
                sta64(X0l + (size_t)b * 3072 + 1024 + c, ap.q);
                sta64(a.zall + ((size_t)(l * 32 + b)) * 2048 + 1024 + c, ap.q);
                u64 ey = *(const u64*)(const void*)(a.eys + (size_t)l * 32 * 1024 + b * 1024 + c);
                sta64(X0l + (size_t)b * 3072 + c, ey);
            }
        }
        gbar(a.gcnt, a.gflag, ++ep);

        // ================= phase B: LSTM cell 0 =================
        {
            // stage A-slice (32 rows x 768 cols of X0l) into LDS, pitch 776
            for (int i = tid; i < 3072; i += 256) {
                int row = i >> 5 >> 2;           // i / 96... compute properly below
                row = i / 96;
                int col = i - row * 96;
                u64 v = lda64((const u64*)(const void*)(X0l + (size_t)row * 3072 + kc * 768) + col);
                *((u64*)(void*)(AS + (size_t)row * 776) + col) = v;
            }
            __syncthreads();
            const unsigned short* Br = a.wc0 + ((size_t)(wave * 1024 + dc * 16 + r)) * 3072 + kc * 768 + q * 8;
            const unsigned short* As0 = AS + (size_t)r * 776 + q * 8;
            const unsigned short* As1 = As0 + 16 * 776;
            floatx4 acc0 = {0.f, 0.f, 0.f, 0.f}, acc1 = acc0;
#pragma unroll 4
            for (int kk = 0; kk < 768; kk += 32) {
                short8 bfr = *(const short8*)(const void*)(Br + kk);
                short8 a0  = *(const short8*)(const void*)(As0 + kk);
                short8 a1  = *(const short8*)(const void*)(As1 + kk);
                acc0 = __builtin_amdgcn_mfma_f32_16x16x32_bf16(a0, bfr, acc0, 0, 0, 0);
                acc1 = __builtin_amdgcn_mfma_f32_16x16x32_bf16(a1, bfr, acc1, 0, 0, 0);
            }
            const int n = wave * 1024 + dc * 16 + r;
            float* gb = a.gp + ((size_t)kc * 4096 + n) * 32;
            {
                union { floatx4 v; u64 q[2]; } u0, u1;
                u0.v = acc0; u1.v = acc1;
                sta64(gb + q * 4, u0.q[0]);      sta64(gb + q * 4 + 2, u0.q[1]);
                sta64(gb + 16 + q * 4, u1.q[0]); sta64(gb + 16 + q * 4 + 2, u1.q[1]);
            }
            __builtin_amdgcn_s_waitcnt(0);
            __syncthreads();
            if (tid == 0) lastf = (arrive(a.cnt0 + dc) == 4 * l + 3);
            __syncthreads();
            if (lastf) {
                const int bb = tid & 31, dp = tid >> 5;
                const int d0 = dc * 16 + dp * 2;
                float gg0[4], gg1[4];
#pragma unroll
                for (int gate = 0; gate < 4; ++gate) {
                    float s0 = a.bs0[gate * 1024 + d0];
                    float s1 = a.bs0[gate * 1024 + d0 + 1];
#pragma unroll
                    for (int kcc = 0; kcc < 4; ++kcc) {
                        s0 += ldaf(a.gp + ((size_t)kcc * 4096 + gate * 1024 + d0) * 32 + bb);
                        s1 += ldaf(a.gp + ((size_t)kcc * 4096 + gate * 1024 + d0 + 1) * 32 + bb);
                    }
                    gg0[gate] = s0; gg1[gate] = s1;
                }
                float cn0 = sigm(gg0[1]) * ldaf(a.c0 + d0 * 32 + bb) + sigm(gg0[0]) * tanhf(gg0[2]);
                float cn1 = sigm(gg1[1]) * ldaf(a.c0 + (d0 + 1) * 32 + bb) + sigm(gg1[0]) * tanhf(gg1[2]);
                staf(a.c0 + d0 * 32 + bb, cn0);
                staf(a.c0 + (d0 + 1) * 32 + bb, cn1);
                unsigned short h0 = f2bf(sigm(gg0[3]) * tanhf(cn0));
                unsigned short h1 = f2bf(sigm(gg1[3]) * tanhf(cn1));
                unsigned int hp = (unsigned int)h0 | ((unsigned int)h1 << 16);
                sta32(X1l + bb * 2048 + d0, hp);
                sta32(X0n + (size_t)bb * 3072 + 2048 + d0, hp);
            }
        }
        gbar(a.gcnt, a.gflag, ++ep);

        // ================= phase C: LSTM cell 1 + next dq =================
        {
            // stage A-slice (32 rows x 512 cols of X1l) into LDS, pitch 520
            for (int i = tid; i < 2048; i += 256) {
                int row = i >> 6;
                int col = i & 63;
                u64 v = lda64((const u64*)(const void*)(X1l + (size_t)row * 2048 + kc * 512) + col);
                *((u64*)(void*)(AS + (size_t)row * 520) + col) = v;
            }
            __syncthreads();
            const unsigned short* Br = a.wc1 + ((size_t)(wave * 1024 + dc * 16 + r)) * 2048 + kc * 512 + q * 8;
            const unsigned short* As0 = AS + (size_t)r * 520 + q * 8;
            const unsigned short* As1 = As0 + 16 * 520;
            floatx4 acc0 = {0.f, 0.f, 0.f, 0.f}, acc1 = acc0;
#pragma unroll 4
            for (int kk = 0; kk < 512; kk += 32) {
                short8 bfr = *(const short8*)(const void*)(Br + kk);
                short8 a0  = *(const short8*)(const void*)(As0 + kk);
                short8 a1  = *(const short8*)(const void*)(As1 + kk);
                acc0 = __builtin_amdgcn_mfma_f32_16x16x32_bf16(a0, bfr, acc0, 0, 0, 0);
                acc1 = __builtin_amdgcn_mfma_f32_16x16x32_bf16(a1, bfr, acc1, 0, 0, 0);
            }
            const int n = wave * 1024 + dc * 16 + r;
            float* gb = a.gp + ((size_t)kc * 4096 + n) * 32;
            {
                union { floatx4 v; u64 q[2]; } u0, u1;
                u0.v = acc0; u1.v = acc1;
                sta64(gb + q * 4, u0.q[0]);      sta64(gb + q * 4 + 2, u0.q[1]);
                sta64(gb + 16 + q * 4, u1.q[0]); sta64(gb + 16 + q * 4 + 2, u1.q[1]);
            }
            // next-step dq on kc==0 blocks (reads z0 written in phase B)
            if (kc == 0 && wave < 2) {
                floatx4 acc = {0.f, 0.f, 0.f, 0.f};
                const unsigned short* Brow = a.wdec + (size_t)(dc * 16 + r) * 1024 + q * 8;
                const unsigned short* Arow = X1l + (size_t)(wave * 16 + r) * 2048 + q * 8;
#pragma unroll 4
                for (int k0 = 0; k0 < 1024; k0 += 32) {
                    short8 bfr = *(const short8*)(const void*)(Brow + k0);
                    short8 afr = lda_s8(Arow + k0);
                    acc = __builtin_amdgcn_mfma_f32_16x16x32_bf16(afr, bfr, acc, 0, 0, 0);
                }
                const int nn = dc * 16 + r;
#pragma unroll
                for (int reg = 0; reg < 4; ++reg) {
                    int m = wave * 16 + q * 4 + reg;
                    dqS[m][r] = tanhf(acc[reg] + a.bdec[nn]);
                }
            }
            __builtin_amdgcn_s_waitcnt(0);
            __syncthreads();
            if (tid == 0) lastf = (arrive(a.cnt1 + dc) == 4 * l + 3);
            __syncthreads();
            if (kc == 0 && tid < 128) {
                const int m = tid >> 2, j = tid & 3;
                union { unsigned int w[2]; u64 qv; } pk;
                pk.w[0] = (unsigned int)f2bf(dqS[m][j * 4 + 0]) | ((unsigned int)f2bf(dqS[m][j * 4 + 1]) << 16);
                pk.w[1] = (unsigned int)f2bf(dqS[m][j * 4 + 2]) | ((unsigned int)f2bf(dqS[m][j * 4 + 3]) << 16);
                sta64(a.dq + (size_t)m * 1024 + dc * 16 + j * 4, pk.qv);
            }
            if (lastf) {
                const int bb = tid & 31, dp = tid >> 5;
                const int d0 = dc * 16 + dp * 2;
                float gg0[4], gg1[4];
#pragma unroll
                for (int gate = 0; gate < 4; ++gate) {
                    float s0 = a.bs1[gate * 1024 + d0];
                    float s1 = a.bs1[gate * 1024 + d0 + 1];
#pragma unroll
                    for (int kcc = 0; kcc < 4; ++kcc) {
                        s0 += ldaf(a.gp + ((size_t)kcc * 4096 + gate * 1024 + d0) * 32 + bb);
                        s1 += ldaf(a.gp + ((size_t)kcc * 4096 + gate * 1024 + d0 + 1) * 32 + bb);
                    }
                    gg0[gate] = s0; gg1[gate] = s1;
                }
                float cn0 = sigm(gg0[1]) * ldaf(a.c1 + d0 * 32 + bb) + sigm(gg0[0]) * tanhf(gg0[2]);
                float cn1 = sigm(gg1[1]) * ldaf(a.c1 + (d0 + 1) * 32 + bb) + sigm(gg1[0]) * tanhf(gg1[2]);
                staf(a.c1 + d0 * 32 + bb, cn0);
                staf(a.c1 + (d0 + 1) * 32 + bb, cn1);
                unsigned short h0 = f2bf(sigm(gg0[3]) * tanhf(cn0));
                unsigned short h1 = f2bf(sigm(gg1[3]) * tanhf(cn1));
                unsigned int hp = (unsigned int)h0 | ((unsigned int)h1 << 16);
                sta32(X1n + bb * 2048 + 1024 + d0, hp);
                sta32(a.zall + ((size_t)(l * 32 + bb)) * 2048 + d0, hp);
            }
        }
        gbar(a.gcnt, a.gflag, ++ep);
    }
}

// ----------------------------------------------------------- CE reduction
__global__ __launch_bounds__(256) void k_ce(const float* __restrict__ y, const float* __restrict__ bout,
                                            const int* __restrict__ ys_pad, float* __restrict__ out) {
    const int rrow = blockIdx.x;
    const int l = rrow >> 5, b = rrow & 31;
    const float* yp = y + (size_t)rrow * 5120;
    const int tid = threadIdx.x;
    __shared__ float red[256];
    float m = -1e30f;
    for (int c = tid; c < 5000; c += 256) m = fmaxf(m, yp[c] + bout[c]);
    red[tid] = m; __syncthreads();
    for (int s = 128; s; s >>= 1) { if (tid < s) red[tid] = fmaxf(red[tid], red[tid + s]); __syncthreads(); }
    const float gmax = red[0]; __syncthreads();
    float ss = 0.f;
    for (int c = tid; c < 5000; c += 256) ss += __expf(yp[c] + bout[c] - gmax);
    red[tid] = ss; __syncthreads();
    for (int s = 128; s; s >>= 1) { if (tid < s) red[tid] += red[tid + s]; __syncthreads(); }
    if (tid == 0) {
        const int tgt = (l < 100) ? ys_pad[b * 100 + l] : 4999;
        const float lt = yp[tgt] + bout[tgt];
        const float ce = logf(red[0]) + gmax - lt;
        atomicAdd(out, ce * (100.0f / 3232.0f));
    }
}

// ---------------------------------------------------------------------------
extern "C" void kernel_launch(void* const* d_in, const int* in_sizes, int n_in,
                              void* d_out, int out_size, void* d_ws, size_t ws_size,
                              hipStream_t stream) {
    const float* hs_pad = (const float*)d_in[0];
    const float* embed  = (const float*)d_in[1];
    const float* Wenc   = (const float*)d_in[2];
    const float* benc   = (const float*)d_in[3];
    const float* Wdec   = (const float*)d_in[4];
    const float* bdec   = (const float*)d_in[5];
    const float* W_ih0  = (const float*)d_in[6];
    const float* W_hh0  = (const float*)d_in[7];
    const float* b_ih0  = (const float*)d_in[8];
    const float* b_hh0  = (const float*)d_in[9];
    const float* W_ih1  = (const float*)d_in[10];
    const float* W_hh1  = (const float*)d_in[11];
    const float* b_ih1  = (const float*)d_in[12];
    const float* b_hh1  = (const float*)d_in[13];
    const float* Wout   = (const float*)d_in[14];
    const float* bout   = (const float*)d_in[15];
    const int*   hlens  = (const int*)d_in[16];
    const int*   ys_pad = (const int*)d_in[17];
    float* out = (float*)d_out;
    uint8_t* ws = (uint8_t*)d_ws;

    constexpr size_t OFF_HS   = 0;
    constexpr size_t OFF_PRE  = OFF_HS   + 26214400;
    constexpr size_t OFF_WC0  = OFF_PRE  + 26214400;
    constexpr size_t OFF_WC1  = OFF_WC0  + 25165824;
    constexpr size_t OFF_WOUT = OFF_WC1  + 16777216;
    constexpr size_t OFF_WENC = OFF_WOUT + 20971520;
    constexpr size_t OFF_WDEC = OFF_WENC + 2097152;
    constexpr size_t OFF_EYS  = OFF_WDEC + 2097152;
    constexpr size_t OFF_ZALL = OFF_EYS  + 6619136;
    constexpr size_t OFF_GP   = OFF_ZALL + 13631488;
    constexpr size_t OFF_PART = OFF_GP   + 2097152;
    constexpr size_t OFF_LMAX = OFF_PART + 1048576;
    constexpr size_t OFF_LSUM = OFF_LMAX + 1024;
    constexpr size_t OFF_DQ   = OFF_LSUM + 1024;
    constexpr size_t OFF_X0R  = OFF_DQ   + 65536;
    constexpr size_t OFF_X1R  = OFF_X0R  + 393216;
    constexpr size_t OFF_C0   = OFF_X1R  + 262144;
    constexpr size_t OFF_C1   = OFF_C0   + 131072;
    constexpr size_t OFF_BS0  = OFF_C1   + 131072;
    constexpr size_t OFF_BS1  = OFF_BS0  + 16384;
    constexpr size_t OFF_CNT  = OFF_BS1  + 16384;
    constexpr size_t OFF_Y    = 0;

    unsigned short* HS   = (unsigned short*)(ws + OFF_HS);
    unsigned short* PRE  = (unsigned short*)(ws + OFF_PRE);
    unsigned short* WC0  = (unsigned short*)(ws + OFF_WC0);
    unsigned short* WC1  = (unsigned short*)(ws + OFF_WC1);
    unsigned short* WOUTP= (unsigned short*)(ws + OFF_WOUT);
    unsigned short* WENC = (unsigned short*)(ws + OFF_WENC);
    unsigned short* WDEC = (unsigned short*)(ws + OFF_WDEC);
    unsigned short* EYS  = (unsigned short*)(ws + OFF_EYS);
    unsigned short* ZALL = (unsigned short*)(ws + OFF_ZALL);
    float* GP    = (float*)(ws + OFF_GP);
    float* PART  = (float*)(ws + OFF_PART);
    float* LMAX  = (float*)(ws + OFF_LMAX);
    float* LSUM  = (float*)(ws + OFF_LSUM);
    unsigned short* DQ  = (unsigned short*)(ws + OFF_DQ);
    unsigned short* X0R = (unsigned short*)(ws + OFF_X0R);
    unsigned short* X1R = (unsigned short*)(ws + OFF_X1R);
    float* C0   = (float*)(ws + OFF_C0);
    float* C1   = (float*)(ws + OFF_C1);
    float* BS0  = (float*)(ws + OFF_BS0);
    float* BS1  = (float*)(ws + OFF_BS1);
    int* CNT    = (int*)(ws + OFF_CNT);
    float* Y = (float*)(ws + OFF_Y);

    auto Zr = [&](void* p, int n_u32) {
        k_zero<<<dim3((n_u32 + 255) / 256), dim3(256), 0, stream>>>((unsigned int*)p, n_u32);
    };

    // ---- setup (re-done every call)
    Zr(X0R, 98304);
    Zr(X1R, 65536);
    Zr(C0, 32768);  Zr(C1, 32768);
    Zr(CNT, 192);
    Zr(d_out, 1);
    Zr(ZALL + (size_t)3232 * 2048, 98304);

    k_conv4<<<dim3(12800), dim3(256), 0, stream>>>(hs_pad, HS, 3276800);
    k_conv4<<<dim3(1024),  dim3(256), 0, stream>>>(Wenc, WENC, 262144);
    k_conv4<<<dim3(1024),  dim3(256), 0, stream>>>(Wdec, WDEC, 262144);
    k_cat2<<<dim3(49152), dim3(256), 0, stream>>>(W_ih0, W_hh0, WC0, 4096, 2048, 1024);
    k_cat2<<<dim3(32768), dim3(256), 0, stream>>>(W_ih1, W_hh1, WC1, 4096, 1024, 1024);
    k_woutpad<<<dim3(40960), dim3(256), 0, stream>>>(Wout, WOUTP);
    k_bsum<<<dim3(32), dim3(256), 0, stream>>>(b_ih0, b_hh0, b_ih1, b_hh1, BS0, BS1);
    k_eys<<<dim3(12928), dim3(256), 0, stream>>>(embed, ys_pad, EYS);

    k_gemm128<<<dim3(8, 100), dim3(256), 0, stream>>>(HS, WENC, 1024, 1024, benc, PRE, (float*)nullptr, 0);
    k_dq<<<dim3(64), dim3(256), 0, stream>>>(WDEC, X1R, 2048, bdec, DQ);

    // ---- the scan: one persistent cooperative kernel, fence-free barriers
    SArgs sa;
    sa.pre = PRE;  sa.hs = HS;  sa.eys = EYS;
    sa.wc0 = WC0;  sa.wc1 = WC1; sa.wdec = WDEC;
    sa.dq = DQ;    sa.x0r = X0R; sa.x1r = X1R; sa.zall = ZALL;
    sa.bdec = bdec; sa.bs0 = BS0; sa.bs1 = BS1;
    sa.c0 = C0;    sa.c1 = C1;  sa.gp = GP;
    sa.part = PART; sa.lmaxg = LMAX; sa.lsumg = LSUM;
    sa.cntA = CNT; sa.cnt0 = CNT + 32; sa.cnt1 = CNT + 96;
    sa.gcnt = CNT + 160; sa.gflag = CNT + 161;
    sa.hlens = hlens;
    void* kp[] = { &sa };
    hipLaunchCooperativeKernel((const void*)k_scan, dim3(256), dim3(256), kp, 0, stream);

    // ---- output projection + CE
    k_gemm128<<<dim3(40, 26), dim3(256), 0, stream>>>(ZALL, WOUTP, 2048, 5120, (const float*)nullptr,
                                                      (unsigned short*)nullptr, Y, 1);
    k_ce<<<dim3(3232), dim3(256), 0, stream>>>(Y, bout, ys_pad, out);
}

// Round 5
// 6933.497 us; speedup vs baseline: 3.1679x; 1.1601x over previous
//
#include <hip/hip_runtime.h>
#include <cstdint>
#include <cstddef>

// ---------------------------------------------------------------------------
// E2E AttDot + 2-layer LSTM decoder + CE loss. B=32,T=400,D=E=1024,V=5000,L=100.
// R5: fp8 e4m3 weights/activations in the scan (L2-resident per-XCD slices),
// pre+hs fully LDS-resident as fp8, R4's fence-free persistent scan retained.
// ---------------------------------------------------------------------------

using short8  = __attribute__((ext_vector_type(8))) short;
using floatx4 = __attribute__((ext_vector_type(4))) float;
using floatx2 = __attribute__((ext_vector_type(2))) float;
typedef unsigned long long u64;

#define DEV __device__ __forceinline__

#if defined(__has_builtin)
#if __has_builtin(__builtin_amdgcn_cvt_pk_f32_fp8) && __has_builtin(__builtin_amdgcn_cvt_pk_fp8_f32)
#define HW_FP8 1
#endif
#endif

DEV float bf2f(unsigned int h) { union { unsigned int u; float f; } v; v.u = h << 16; return v.f; }
DEV unsigned short f2bf(float f) {
    union { float f; unsigned int u; } v; v.f = f;
    return (unsigned short)((v.u + 0x7fffu + ((v.u >> 16) & 1u)) >> 16);
}
DEV float sigm(float x) { return 1.0f / (1.0f + __expf(-x)); }

// ---- fp8 e4m3 software codecs (fallback + setup use)
DEV float fp8tof_sw(unsigned int b) {
    unsigned int s = (b & 0x80u) << 24;
    unsigned int em = b & 0x7fu;
    float vn = __uint_as_float(s | ((em + 960u) << 20));
    float vd = (float)(int)em * 0x1p-9f;
    vd = s ? -vd : vd;
    return (em >= 8u) ? vn : vd;
}
DEV unsigned int f2fp8_sw(float f) {
    unsigned int u = __float_as_uint(f);
    unsigned int s = (u >> 24) & 0x80u;
    unsigned int a = u & 0x7fffffffu;
    if (a >= 0x43e00000u) return s | 0x7eu;            // clamp +-448
    if (a < 0x3c800000u) {                              // denorm: m = rne(|f|*512)
        unsigned int mi = (unsigned int)(__uint_as_float(a) * 512.0f + 0.5f);
        return s | mi;
    }
    unsigned int lsb = (a >> 20) & 1u;
    a += 0x0007ffffu + lsb;
    unsigned int e = (a >> 23) - 120u;
    unsigned int m = (a >> 20) & 7u;
    return s | (e << 3) | m;
}
DEV void un4(unsigned int w, float* o) {
#ifdef HW_FP8
    floatx2 lo = __builtin_amdgcn_cvt_pk_f32_fp8((int)w, false);
    floatx2 hi = __builtin_amdgcn_cvt_pk_f32_fp8((int)w, true);
    o[0] = lo.x; o[1] = lo.y; o[2] = hi.x; o[3] = hi.y;
#else
    o[0] = fp8tof_sw(w & 0xffu); o[1] = fp8tof_sw((w >> 8) & 0xffu);
    o[2] = fp8tof_sw((w >> 16) & 0xffu); o[3] = fp8tof_sw(w >> 24);
#endif
}
DEV unsigned int pack4fp8(float a, float b, float c, float d) {
#ifdef HW_FP8
    int w = __builtin_amdgcn_cvt_pk_fp8_f32(a, b, 0, false);
    w = __builtin_amdgcn_cvt_pk_fp8_f32(c, d, w, true);
    return (unsigned int)w;
#else
    return f2fp8_sw(a) | (f2fp8_sw(b) << 8) | (f2fp8_sw(c) << 16) | (f2fp8_sw(d) << 24);
#endif
}
DEV unsigned char f2fp8_1(float v) {
#ifdef HW_FP8
    return (unsigned char)((unsigned int)__builtin_amdgcn_cvt_pk_fp8_f32(v, v, 0, false) & 0xffu);
#else
    return (unsigned char)f2fp8_sw(v);
#endif
}
DEV u64 pack4bf16(float a, float b, float c, float d) {
    union { unsigned int w[2]; u64 q; } u;
    u.w[0] = (unsigned int)f2bf(a) | ((unsigned int)f2bf(b) << 16);
    u.w[1] = (unsigned int)f2bf(c) | ((unsigned int)f2bf(d) << 16);
    return u.q;
}

// relaxed agent-scope accessors (per-access coherence, no cache-wide inv)
DEV u64  lda64(const void* p) { return __hip_atomic_load((const u64*)p, __ATOMIC_RELAXED, __HIP_MEMORY_SCOPE_AGENT); }
DEV void sta64(void* p, u64 v) { __hip_atomic_store((u64*)p, v, __ATOMIC_RELAXED, __HIP_MEMORY_SCOPE_AGENT); }
DEV void sta32(void* p, unsigned int v) { __hip_atomic_store((unsigned int*)p, v, __ATOMIC_RELAXED, __HIP_MEMORY_SCOPE_AGENT); }
DEV float ldaf(const void* p) { return __hip_atomic_load((const float*)p, __ATOMIC_RELAXED, __HIP_MEMORY_SCOPE_AGENT); }
DEV void staf(void* p, float v) { __hip_atomic_store((float*)p, v, __ATOMIC_RELAXED, __HIP_MEMORY_SCOPE_AGENT); }
DEV int  arrive(int* p) { return __hip_atomic_fetch_add(p, 1, __ATOMIC_RELAXED, __HIP_MEMORY_SCOPE_AGENT); }

// ---------------------------------------------------------------- utilities
__global__ __launch_bounds__(256) void k_zero(unsigned int* p, int n) {
    int i = blockIdx.x * 256 + threadIdx.x;
    if (i < n) p[i] = 0u;
}

__global__ __launch_bounds__(256) void k_conv4(const float* __restrict__ in,
                                               unsigned short* __restrict__ out, int n4) {
    int i = blockIdx.x * 256 + threadIdx.x;
    if (i >= n4) return;
    float4 v = ((const float4*)in)[i];
    unsigned int w0 = (unsigned int)f2bf(v.x) | ((unsigned int)f2bf(v.y) << 16);
    unsigned int w1 = (unsigned int)f2bf(v.z) | ((unsigned int)f2bf(v.w) << 16);
    ((uint2*)(void*)out)[i] = make_uint2(w0, w1);
}

// hs: f32 -> bf16 (for pre-GEMM) + fp8 (for attention)
__global__ __launch_bounds__(256) void k_convhs(const float* __restrict__ in,
                                                unsigned short* __restrict__ obf,
                                                unsigned int* __restrict__ o8, int n4) {
    int i = blockIdx.x * 256 + threadIdx.x;
    if (i >= n4) return;
    float4 v = ((const float4*)in)[i];
    unsigned int w0 = (unsigned int)f2bf(v.x) | ((unsigned int)f2bf(v.y) << 16);
    unsigned int w1 = (unsigned int)f2bf(v.z) | ((unsigned int)f2bf(v.w) << 16);
    ((uint2*)(void*)obf)[i] = make_uint2(w0, w1);
    o8[i] = pack4fp8(v.x, v.y, v.z, v.w);
}

__global__ __launch_bounds__(256) void k_conv8(const float* __restrict__ in,
                                               unsigned int* __restrict__ o8, int n4) {
    int i = blockIdx.x * 256 + threadIdx.x;
    if (i >= n4) return;
    float4 v = ((const float4*)in)[i];
    o8[i] = pack4fp8(v.x, v.y, v.z, v.w);
}

// fp8 [N][Ka+Kb] from f32 A[N][Ka], B[N][Kb] (Ka,Kb multiples of 4)
__global__ __launch_bounds__(256) void k_cat2_8(const float* __restrict__ A, const float* __restrict__ Bsrc,
                                                unsigned int* __restrict__ dst, int N, int Ka, int Kb) {
    int idx = blockIdx.x * 256 + threadIdx.x;
    int K4 = (Ka + Kb) >> 2;
    if (idx >= N * K4) return;
    int n = idx / K4, k = (idx - n * K4) * 4;
    const float* src = (k < Ka) ? (A + (size_t)n * Ka + k) : (Bsrc + (size_t)n * Kb + (k - Ka));
    dst[idx] = pack4fp8(src[0], src[1], src[2], src[3]);
}

__global__ __launch_bounds__(256) void k_woutpad(const float* __restrict__ W, unsigned short* __restrict__ dst) {
    int idx = blockIdx.x * 256 + threadIdx.x;
    if (idx >= 5120 * 2048) return;
    int n = idx >> 11, k = idx & 2047;
    dst[idx] = (n < 5000) ? f2bf(W[(size_t)n * 2048 + k]) : (unsigned short)0;
}

__global__ __launch_bounds__(256) void k_bsum(const float* a0, const float* b0, const float* a1, const float* b1,
                                              float* s0, float* s1) {
    int i = blockIdx.x * 256 + threadIdx.x;
    if (i < 4096) s0[i] = a0[i] + b0[i];
    else if (i < 8192) s1[i - 4096] = a1[i - 4096] + b1[i - 4096];
}

// eys fp8 [l][b][1024]
__global__ __launch_bounds__(256) void k_eys8(const float* __restrict__ embed, const int* __restrict__ ys_pad,
                                              unsigned int* __restrict__ eys8) {
    int idx = blockIdx.x * 256 + threadIdx.x;
    if (idx >= 3232 * 256) return;
    int rb = idx >> 8, c4 = idx & 255;
    int l = rb >> 5, b = rb & 31;
    int tok = (l == 0) ? 4999 : ys_pad[b * 100 + (l - 1)];
    const float* e = embed + (size_t)tok * 1024 + c4 * 4;
    eys8[idx] = pack4fp8(e[0], e[1], e[2], e[3]);
}

// dq init: z0=0 -> dq = tanh(bdec)
__global__ __launch_bounds__(256) void k_dq0(const float* __restrict__ bdec, unsigned short* __restrict__ dq) {
    int idx = blockIdx.x * 256 + threadIdx.x;
    if (idx >= 32768) return;
    dq[idx] = f2bf(tanhf(bdec[idx & 1023]));
}

// --------------------------------------------------- big 128x128 MFMA GEMM
// mode0: o8 = fp8(tanh(C+bias));  mode1: of32 = C
__global__ __launch_bounds__(256) void k_gemm128(
    const unsigned short* __restrict__ A, const unsigned short* __restrict__ B,
    int K, int N, const float* __restrict__ bias,
    unsigned char* __restrict__ o8, float* __restrict__ of32, int mode) {
    __shared__ uint4 Ab[512];
    __shared__ uint4 Bb[512];
    const int tid = threadIdx.x;
    const int lane = tid & 63, wave = tid >> 6;
    const int r = lane & 15, q = lane >> 4;
    const int wm = wave >> 1, wn = wave & 1;
    const size_t am0 = (size_t)blockIdx.y * 128;
    const size_t bn0 = (size_t)blockIdx.x * 128;
    floatx4 zf = {0.f, 0.f, 0.f, 0.f};
    floatx4 acc[4][4];
#pragma unroll
    for (int i = 0; i < 4; i++)
#pragma unroll
        for (int j = 0; j < 4; j++) acc[i][j] = zf;

    for (int k0 = 0; k0 < K; k0 += 32) {
        __syncthreads();
#pragma unroll
        for (int i = 0; i < 2; ++i) {
            int idx = i * 256 + tid;
            int qq = idx & 3, rr = idx >> 2;
            int slot = (rr >> 4) * 64 + ((qq << 4) | (rr & 15));
            Ab[slot] = *(const uint4*)(const void*)(A + (am0 + rr) * K + k0 + qq * 8);
            Bb[slot] = *(const uint4*)(const void*)(B + (bn0 + rr) * K + k0 + qq * 8);
        }
        __syncthreads();
        short8 af[4], bf[4];
#pragma unroll
        for (int t = 0; t < 4; t++) af[t] = *(const short8*)(const void*)&Ab[(wm * 4 + t) * 64 + lane];
#pragma unroll
        for (int t = 0; t < 4; t++) bf[t] = *(const short8*)(const void*)&Bb[(wn * 4 + t) * 64 + lane];
#pragma unroll
        for (int tm = 0; tm < 4; tm++)
#pragma unroll
            for (int tn = 0; tn < 4; tn++)
                acc[tm][tn] = __builtin_amdgcn_mfma_f32_16x16x32_bf16(af[tm], bf[tn], acc[tm][tn], 0, 0, 0);
    }
#pragma unroll
    for (int tm = 0; tm < 4; tm++) {
#pragma unroll
        for (int tn = 0; tn < 4; tn++) {
            int col = (int)bn0 + wn * 64 + tn * 16 + r;
#pragma unroll
            for (int reg = 0; reg < 4; ++reg) {
                size_t row = am0 + wm * 64 + tm * 16 + q * 4 + reg;
                float v = acc[tm][tn][reg];
                if (mode == 0) {
                    v = tanhf(v + bias[col]);
                    o8[row * (size_t)N + col] = f2fp8_1(v);
                } else {
                    of32[row * (size_t)N + col] = v;
                }
            }
        }
    }
}

// ------------------------------------------------- persistent scan kernel
struct SArgs {
    const unsigned char* pre8;   // [12800][1024] fp8
    const unsigned char* hs8;    // [12800][1024] fp8
    const unsigned char* eys8;   // [3232][1024] fp8
    const unsigned char* wc0;    // [4096][3072] fp8
    const unsigned char* wc1;    // [4096][2048] fp8
    const unsigned char* wdec;   // [1024][1024] fp8
    unsigned short* dq;          // [32][1024] bf16
    unsigned char* x0r;          // [2][32][3072] fp8
    unsigned char* x1r;          // [2][32][2048] fp8
    unsigned short* zall;        // [3328][2048] bf16
    const float* bdec; const float* bs0; const float* bs1;
    float* c0; float* c1;
    float* gp;                   // [4][4096][32] f32
    float* part; float* lmaxg; float* lsumg;
    int* cntA; int* cnt0; int* cnt1; int* gcnt; int* gflag;
    const int* hlens;
};

DEV void gbar(int* gcnt, int* gflag, int ep) {
    __builtin_amdgcn_s_waitcnt(0);
    __syncthreads();
    if (threadIdx.x == 0) {
        int old = arrive(gcnt);
        if (old == ep * 256 - 1) {
            __hip_atomic_store(gflag, ep, __ATOMIC_RELAXED, __HIP_MEMORY_SCOPE_AGENT);
        } else {
            while (__hip_atomic_load(gflag, __ATOMIC_RELAXED, __HIP_MEMORY_SCOPE_AGENT) < ep)
                __builtin_amdgcn_s_sleep(1);
        }
    }
    __syncthreads();
}

__global__ __launch_bounds__(256, 1) void k_scan(SArgs a) {
    const int blk = blockIdx.x, tid = threadIdx.x;
    const int lane = tid & 63, wave = tid >> 6;
    const int b = blk >> 3, ch = blk & 7;       // attention role
    const int dc = blk >> 2, kc = blk & 3;      // cell role
    const int r = lane & 15, q = lane >> 4;
    const int hlen = a.hlens[b];

    __shared__ __align__(16) unsigned char preS[51200];  // 50x1024 fp8 (whole slice)
    __shared__ __align__(16) unsigned char hsS[51200];   // 50x1024 fp8 (whole slice)
    __shared__ __align__(16) unsigned char AS[24832];    // staging (B:32x776, C:32x520, A:dq 2KB)
    __shared__ float dqS[32][16];
    __shared__ float e4[50][4];
    __shared__ float es[52];
    __shared__ float ps[52];
    __shared__ int lastf;

    // one-time LDS fill: pre8/hs8 [b][ch*50 .. +49][:]
    {
        const u64* psrc = (const u64*)(const void*)(a.pre8 + (size_t)(b * 400 + ch * 50) * 1024);
        const u64* hsrc = (const u64*)(const void*)(a.hs8 + (size_t)(b * 400 + ch * 50) * 1024);
        u64* pd = (u64*)(void*)preS;
        u64* hd = (u64*)(void*)hsS;
        for (int i = tid; i < 6400; i += 256) { pd[i] = psrc[i]; hd[i] = hsrc[i]; }
    }
    __syncthreads();

    int ep = 0;
    for (int l = 0; l < 101; ++l) {
        unsigned char* X0l = a.x0r + (size_t)(l & 1) * 98304;
        unsigned char* X0n = a.x0r + (size_t)((l + 1) & 1) * 98304;
        unsigned char* X1l = a.x1r + (size_t)(l & 1) * 65536;
        unsigned char* X1n = a.x1r + (size_t)((l + 1) & 1) * 65536;

        // ================= phase A: attention =================
        {
            // stage dq[b] (2 KB bf16) into AS once per block
            ((u64*)(void*)AS)[tid] = (tid < 256) ? lda64((const char*)(const void*)(a.dq + b * 1024) + tid * 8) : 0;
            __syncthreads();
            float dqf[16];
            {
                const unsigned int* dw = (const unsigned int*)(const void*)AS + lane * 8;
#pragma unroll
                for (int i = 0; i < 8; ++i) {
                    unsigned int w = dw[i];
                    dqf[2 * i] = bf2f(w & 0xffffu);
                    dqf[2 * i + 1] = bf2f(w >> 16);
                }
            }
            for (int tl = wave; tl < 50; tl += 4) {
                uint4 v = *(const uint4*)(const void*)(preS + tl * 1024 + lane * 16);
                float x[16];
                un4(v.x, x); un4(v.y, x + 4); un4(v.z, x + 8); un4(v.w, x + 12);
                float s = 0.f;
#pragma unroll
                for (int i = 0; i < 16; ++i) s += x[i] * dqf[i];
                s += __shfl_xor(s, 1, 64);
                s += __shfl_xor(s, 2, 64);
                s += __shfl_xor(s, 4, 64);
                s += __shfl_xor(s, 8, 64);
                if ((lane & 15) == 0) e4[tl][lane >> 4] = s;
            }
            __syncthreads();
            if (tid < 50) {
                float4 v = *(const float4*)(const void*)e4[tid];
                float e = v.x + v.y + v.z + v.w;
                int t = ch * 50 + tid;
                es[tid] = (t < hlen) ? 2.0f * e : -1e30f;
            }
            __syncthreads();
            float lmax = -1e30f;
#pragma unroll
            for (int i = 0; i < 50; ++i) lmax = fmaxf(lmax, es[i]);
            if (tid < 50) ps[tid] = (es[tid] > -5e29f) ? __expf(es[tid] - lmax) : 0.f;
            __syncthreads();
            if (tid == 0) {
                float ssum = 0.f;
                for (int i = 0; i < 50; ++i) ssum += ps[i];
                staf(a.lmaxg + b * 8 + ch, lmax);
                staf(a.lsumg + b * 8 + ch, ssum);
            }
            const int c = tid * 4;
            float a0 = 0.f, a1 = 0.f, a2 = 0.f, a3 = 0.f;
            for (int tl = 0; tl < 50; ++tl) {
                float p = ps[tl];
                unsigned int h = *(const unsigned int*)(const void*)(hsS + tl * 1024 + c);
                float x[4];
                un4(h, x);
                a0 += p * x[0]; a1 += p * x[1]; a2 += p * x[2]; a3 += p * x[3];
            }
            {
                float* pb = a.part + ((size_t)(b * 8 + ch)) * 1024 + c;
                union { float f[2]; u64 q; } p0, p1;
                p0.f[0] = a0; p0.f[1] = a1; p1.f[0] = a2; p1.f[1] = a3;
                sta64(pb, p0.q); sta64(pb + 2, p1.q);
            }
            __builtin_amdgcn_s_waitcnt(0);
            __syncthreads();
            if (tid == 0) lastf = (arrive(a.cntA + b) == 8 * l + 7);
            __syncthreads();
            if (lastf) {
                float lm[8], ls[8];
#pragma unroll
                for (int i = 0; i < 8; ++i) {
                    lm[i] = ldaf(a.lmaxg + b * 8 + i);
                    ls[i] = ldaf(a.lsumg + b * 8 + i);
                }
                float gm = -1e30f;
#pragma unroll
                for (int i = 0; i < 8; ++i) gm = fmaxf(gm, lm[i]);
                float Zs = 0.f;
#pragma unroll
                for (int i = 0; i < 8; ++i) Zs += ls[i] * __expf(lm[i] - gm);
                const float inv = 1.0f / Zs;
                float o0 = 0.f, o1 = 0.f, o2 = 0.f, o3 = 0.f;
#pragma unroll
                for (int i = 0; i < 8; ++i) {
                    float coef = __expf(lm[i] - gm) * inv;
                    const float* qp = a.part + ((size_t)(b * 8 + i)) * 1024 + c;
                    union { u64 q; float f[2]; } u0, u1;
                    u0.q = lda64(qp); u1.q = lda64(qp + 2);
                    o0 += coef * u0.f[0]; o1 += coef * u0.f[1];
                    o2 += coef * u1.f[0]; o3 += coef * u1.f[1];
                }
                sta32(X0l + (size_t)b * 3072 + 1024 + c, pack4fp8(o0, o1, o2, o3));
                sta64(a.zall + ((size_t)(l * 32 + b)) * 2048 + 1024 + c, pack4bf16(o0, o1, o2, o3));
                unsigned int ey = *(const unsigned int*)(const void*)(a.eys8 + ((size_t)(l * 32 + b)) * 1024 + c);
                sta32(X0l + (size_t)b * 3072 + c, ey);
            }
        }
        gbar(a.gcnt, a.gflag, ++ep);

        // ================= phase B: LSTM cell 0 =================
        {
            for (int i = tid; i < 3072; i += 256) {   // 32 rows x 96 u64 (768 B)
                int row = i / 96, col = i - row * 96;
                ((u64*)(void*)AS)[row * 97 + col] =
                    lda64((const char*)X0l + (size_t)row * 3072 + kc * 768 + col * 8);
            }
            __syncthreads();
            const unsigned char* Br = a.wc0 + (size_t)(wave * 1024 + dc * 16 + r) * 3072 + kc * 768 + q * 8;
            const unsigned char* A0 = AS + r * 776 + q * 8;
            const unsigned char* A1 = A0 + 16 * 776;
            floatx4 acc0 = {0.f, 0.f, 0.f, 0.f}, acc1 = acc0;
#pragma unroll 4
            for (int kk = 0; kk < 768; kk += 32) {
                long long bfr = *(const long long*)(const void*)(Br + kk);
                long long a0 = *(const long long*)(const void*)(A0 + kk);
                long long a1 = *(const long long*)(const void*)(A1 + kk);
                acc0 = __builtin_amdgcn_mfma_f32_16x16x32_fp8_fp8(a0, bfr, acc0, 0, 0, 0);
                acc1 = __builtin_amdgcn_mfma_f32_16x16x32_fp8_fp8(a1, bfr, acc1, 0, 0, 0);
            }
            const int n = wave * 1024 + dc * 16 + r;
            float* gb = a.gp + ((size_t)kc * 4096 + n) * 32;
            {
                union { floatx4 v; u64 q2[2]; } u0, u1;
                u0.v = acc0; u1.v = acc1;
                sta64(gb + q * 4, u0.q2[0]);      sta64(gb + q * 4 + 2, u0.q2[1]);
                sta64(gb + 16 + q * 4, u1.q2[0]); sta64(gb + 16 + q * 4 + 2, u1.q2[1]);
            }
            __builtin_amdgcn_s_waitcnt(0);
            __syncthreads();
            if (tid == 0) lastf = (arrive(a.cnt0 + dc) == 4 * l + 3);
            __syncthreads();
            if (lastf && tid < 128) {
                const int bb = tid & 31, dg = tid >> 5;
                const int d0 = dc * 16 + dg * 4;
                float z[4];
#pragma unroll
                for (int j = 0; j < 4; ++j) {
                    const int d = d0 + j;
                    float g0 = a.bs0[d], g1 = a.bs0[1024 + d], g2 = a.bs0[2048 + d], g3 = a.bs0[3072 + d];
#pragma unroll
                    for (int kcc = 0; kcc < 4; ++kcc) {
                        const float* gpp = a.gp + (size_t)kcc * 131072;
                        g0 += ldaf(gpp + (size_t)d * 32 + bb);
                        g1 += ldaf(gpp + (size_t)(1024 + d) * 32 + bb);
                        g2 += ldaf(gpp + (size_t)(2048 + d) * 32 + bb);
                        g3 += ldaf(gpp + (size_t)(3072 + d) * 32 + bb);
                    }
                    float cn = sigm(g1) * ldaf(a.c0 + d * 32 + bb) + sigm(g0) * tanhf(g2);
                    staf(a.c0 + d * 32 + bb, cn);
                    z[j] = sigm(g3) * tanhf(cn);
                }
                unsigned int zp = pack4fp8(z[0], z[1], z[2], z[3]);
                sta32(X1l + bb * 2048 + d0, zp);
                sta32(X0n + (size_t)bb * 3072 + 2048 + d0, zp);
            }
        }
        gbar(a.gcnt, a.gflag, ++ep);

        // ================= phase C: LSTM cell 1 + next dq =================
        {
            for (int i = tid; i < 2048; i += 256) {   // 32 rows x 64 u64 (512 B)
                int row = i >> 6, col = i & 63;
                ((u64*)(void*)AS)[row * 65 + col] =
                    lda64((const char*)X1l + (size_t)row * 2048 + kc * 512 + col * 8);
            }
            __syncthreads();
            const unsigned char* Br = a.wc1 + (size_t)(wave * 1024 + dc * 16 + r) * 2048 + kc * 512 + q * 8;
            const unsigned char* A0 = AS + r * 520 + q * 8;
            const unsigned char* A1 = A0 + 16 * 520;
            floatx4 acc0 = {0.f, 0.f, 0.f, 0.f}, acc1 = acc0;
#pragma unroll 4
            for (int kk = 0; kk < 512; kk += 32) {
                long long bfr = *(const long long*)(const void*)(Br + kk);
                long long a0 = *(const long long*)(const void*)(A0 + kk);
                long long a1 = *(const long long*)(const void*)(A1 + kk);
                acc0 = __builtin_amdgcn_mfma_f32_16x16x32_fp8_fp8(a0, bfr, acc0, 0, 0, 0);
                acc1 = __builtin_amdgcn_mfma_f32_16x16x32_fp8_fp8(a1, bfr, acc1, 0, 0, 0);
            }
            const int n = wave * 1024 + dc * 16 + r;
            float* gb = a.gp + ((size_t)kc * 4096 + n) * 32;
            {
                union { floatx4 v; u64 q2[2]; } u0, u1;
                u0.v = acc0; u1.v = acc1;
                sta64(gb + q * 4, u0.q2[0]);      sta64(gb + q * 4 + 2, u0.q2[1]);
                sta64(gb + 16 + q * 4, u1.q2[0]); sta64(gb + 16 + q * 4 + 2, u1.q2[1]);
            }
            // next-step dq on kc==0 blocks, waves 0-1 (z0 from phase B)
            if (kc == 0 && wave < 2) {
                floatx4 acc = {0.f, 0.f, 0.f, 0.f};
                const unsigned char* Brow = a.wdec + (size_t)(dc * 16 + r) * 1024 + q * 8;
                const char* Arow = (const char*)X1l + (size_t)(wave * 16 + r) * 2048 + q * 8;
#pragma unroll 4
                for (int k0 = 0; k0 < 1024; k0 += 32) {
                    long long bfr = *(const long long*)(const void*)(Brow + k0);
                    long long afr = (long long)lda64(Arow + k0);
                    acc = __builtin_amdgcn_mfma_f32_16x16x32_fp8_fp8(afr, bfr, acc, 0, 0, 0);
                }
                const int nn = dc * 16 + r;
#pragma unroll
                for (int reg = 0; reg < 4; ++reg)
                    dqS[wave * 16 + q * 4 + reg][r] = tanhf(acc[reg] + a.bdec[nn]);
            }
            __builtin_amdgcn_s_waitcnt(0);
            __syncthreads();
            if (tid == 0) lastf = (arrive(a.cnt1 + dc) == 4 * l + 3);
            __syncthreads();
            if (kc == 0 && tid < 128) {
                const int m = tid >> 2, j = tid & 3;
                sta64(a.dq + (size_t)m * 1024 + dc * 16 + j * 4,
                      pack4bf16(dqS[m][j * 4], dqS[m][j * 4 + 1], dqS[m][j * 4 + 2], dqS[m][j * 4 + 3]));
            }
            if (lastf && tid < 128) {
                const int bb = tid & 31, dg = tid >> 5;
                const int d0 = dc * 16 + dg * 4;
                float z[4];
#pragma unroll
                for (int j = 0; j < 4; ++j) {
                    const int d = d0 + j;
                    float g0 = a.bs1[d], g1 = a.bs1[1024 + d], g2 = a.bs1[2048 + d], g3 = a.bs1[3072 + d];
#pragma unroll
                    for (int kcc = 0; kcc < 4; ++kcc) {
                        const float* gpp = a.gp + (size_t)kcc * 131072;
                        g0 += ldaf(gpp + (size_t)d * 32 + bb);
                        g1 += ldaf(gpp + (size_t)(1024 + d) * 32 + bb);
                        g2 += ldaf(gpp + (size_t)(2048 + d) * 32 + bb);
                        g3 += ldaf(gpp + (size_t)(3072 + d) * 32 + bb);
                    }
                    float cn = sigm(g1) * ldaf(a.c1 + d * 32 + bb) + sigm(g0) * tanhf(g2);
                    staf(a.c1 + d * 32 + bb, cn);
                    z[j] = sigm(g3) * tanhf(cn);
                }
                sta32(X1n + bb * 2048 + 1024 + d0, pack4fp8(z[0], z[1], z[2], z[3]));
                sta64(a.zall + ((size_t)(l * 32 + bb)) * 2048 + d0, pack4bf16(z[0], z[1], z[2], z[3]));
            }
        }
        gbar(a.gcnt, a.gflag, ++ep);
    }
}

// ----------------------------------------------------------- CE reduction
__global__ __launch_bounds__(256) void k_ce(const float* __restrict__ y, const float* __restrict__ bout,
                                            const int* __restrict__ ys_pad, float* __restrict__ out) {
    const int rrow = blockIdx.x;
    const int l = rrow >> 5, b = rrow & 31;
    const float* yp = y + (size_t)rrow * 5120;
    const int tid = threadIdx.x;
    __shared__ float red[256];
    float m = -1e30f;
    for (int c = tid; c < 5000; c += 256) m = fmaxf(m, yp[c] + bout[c]);
    red[tid] = m; __syncthreads();
    for (int s = 128; s; s >>= 1) { if (tid < s) red[tid] = fmaxf(red[tid], red[tid + s]); __syncthreads(); }
    const float gmax = red[0]; __syncthreads();
    float ss = 0.f;
    for (int c = tid; c < 5000; c += 256) ss += __expf(yp[c] + bout[c] - gmax);
    red[tid] = ss; __syncthreads();
    for (int s = 128; s; s >>= 1) { if (tid < s) red[tid] += red[tid + s]; __syncthreads(); }
    if (tid == 0) {
        const int tgt = (l < 100) ? ys_pad[b * 100 + l] : 4999;
        const float lt = yp[tgt] + bout[tgt];
        const float ce = logf(red[0]) + gmax - lt;
        atomicAdd(out, ce * (100.0f / 3232.0f));
    }
}

// ---------------------------------------------------------------------------
extern "C" void kernel_launch(void* const* d_in, const int* in_sizes, int n_in,
                              void* d_out, int out_size, void* d_ws, size_t ws_size,
                              hipStream_t stream) {
    const float* hs_pad = (const float*)d_in[0];
    const float* embed  = (const float*)d_in[1];
    const float* Wenc   = (const float*)d_in[2];
    const float* benc   = (const float*)d_in[3];
    const float* Wdec   = (const float*)d_in[4];
    const float* bdec   = (const float*)d_in[5];
    const float* W_ih0  = (const float*)d_in[6];
    const float* W_hh0  = (const float*)d_in[7];
    const float* b_ih0  = (const float*)d_in[8];
    const float* b_hh0  = (const float*)d_in[9];
    const float* W_ih1  = (const float*)d_in[10];
    const float* W_hh1  = (const float*)d_in[11];
    const float* b_ih1  = (const float*)d_in[12];
    const float* b_hh1  = (const float*)d_in[13];
    const float* Wout   = (const float*)d_in[14];
    const float* bout   = (const float*)d_in[15];
    const int*   hlens  = (const int*)d_in[16];
    const int*   ys_pad = (const int*)d_in[17];
    float* out = (float*)d_out;
    uint8_t* ws = (uint8_t*)d_ws;

    // layout: dead-by-final-GEMM buffers first (Y f32 68.2MB aliases them)
    constexpr size_t OFF_HS    = 0;                        // 26,214,400 bf16 hs
    constexpr size_t OFF_PRE8  = OFF_HS    + 26214400;     // 13,107,200
    constexpr size_t OFF_HS8   = OFF_PRE8  + 13107200;     // 13,107,200
    constexpr size_t OFF_WC08  = OFF_HS8   + 13107200;     // 12,582,912
    constexpr size_t OFF_WC18  = OFF_WC08  + 12582912;     //  8,388,608
    constexpr size_t OFF_WDEC8 = OFF_WC18  + 8388608;      //  1,048,576
    constexpr size_t OFF_WENC  = OFF_WDEC8 + 1048576;      //  2,097,152 bf16
    constexpr size_t OFF_EYS8  = OFF_WENC  + 2097152;      //  3,309,568
    constexpr size_t OFF_ZALL  = OFF_EYS8  + 3309568;      // 13,631,488 bf16
    constexpr size_t OFF_WOUT  = OFF_ZALL  + 13631488;     // 20,971,520 bf16
    constexpr size_t OFF_GP    = OFF_WOUT  + 20971520;     //  2,097,152 f32
    constexpr size_t OFF_PART  = OFF_GP    + 2097152;      //  1,048,576
    constexpr size_t OFF_LMAX  = OFF_PART  + 1048576;      //  1,024
    constexpr size_t OFF_LSUM  = OFF_LMAX  + 1024;         //  1,024
    constexpr size_t OFF_DQ    = OFF_LSUM  + 1024;         //  65,536
    constexpr size_t OFF_X0R   = OFF_DQ    + 65536;        //  196,608
    constexpr size_t OFF_X1R   = OFF_X0R   + 196608;       //  131,072
    constexpr size_t OFF_C0    = OFF_X1R   + 131072;       //  131,072
    constexpr size_t OFF_C1    = OFF_C0    + 131072;       //  131,072
    constexpr size_t OFF_BS0   = OFF_C1    + 131072;       //  16,384
    constexpr size_t OFF_BS1   = OFF_BS0   + 16384;        //  16,384
    constexpr size_t OFF_CNT   = OFF_BS1   + 16384;        //  768
    constexpr size_t OFF_Y     = 0;

    unsigned short* HS    = (unsigned short*)(ws + OFF_HS);
    unsigned char*  PRE8  = (unsigned char*)(ws + OFF_PRE8);
    unsigned char*  HS8   = (unsigned char*)(ws + OFF_HS8);
    unsigned char*  WC08  = (unsigned char*)(ws + OFF_WC08);
    unsigned char*  WC18  = (unsigned char*)(ws + OFF_WC18);
    unsigned char*  WDEC8 = (unsigned char*)(ws + OFF_WDEC8);
    unsigned short* WENC  = (unsigned short*)(ws + OFF_WENC);
    unsigned char*  EYS8  = (unsigned char*)(ws + OFF_EYS8);
    unsigned short* ZALL  = (unsigned short*)(ws + OFF_ZALL);
    unsigned short* WOUTP = (unsigned short*)(ws + OFF_WOUT);
    float* GP    = (float*)(ws + OFF_GP);
    float* PART  = (float*)(ws + OFF_PART);
    float* LMAX  = (float*)(ws + OFF_LMAX);
    float* LSUM  = (float*)(ws + OFF_LSUM);
    unsigned short* DQ  = (unsigned short*)(ws + OFF_DQ);
    unsigned char*  X0R = (unsigned char*)(ws + OFF_X0R);
    unsigned char*  X1R = (unsigned char*)(ws + OFF_X1R);
    float* C0   = (float*)(ws + OFF_C0);
    float* C1   = (float*)(ws + OFF_C1);
    float* BS0  = (float*)(ws + OFF_BS0);
    float* BS1  = (float*)(ws + OFF_BS1);
    int* CNT    = (int*)(ws + OFF_CNT);
    float* Y = (float*)(ws + OFF_Y);

    auto Zr = [&](void* p, int n_u32) {
        k_zero<<<dim3((n_u32 + 255) / 256), dim3(256), 0, stream>>>((unsigned int*)p, n_u32);
    };

    // ---- setup (re-done every call)
    Zr(X0R, 49152);
    Zr(X1R, 32768);
    Zr(C0, 32768);  Zr(C1, 32768);
    Zr(CNT, 192);
    Zr(d_out, 1);
    Zr(ZALL + (size_t)3232 * 2048, 98304);   // zall pad rows

    k_convhs<<<dim3(12800), dim3(256), 0, stream>>>(hs_pad, HS, (unsigned int*)(void*)HS8, 3276800);
    k_conv4<<<dim3(1024),  dim3(256), 0, stream>>>(Wenc, WENC, 262144);
    k_conv8<<<dim3(1024),  dim3(256), 0, stream>>>(Wdec, (unsigned int*)(void*)WDEC8, 262144);
    k_cat2_8<<<dim3(12288), dim3(256), 0, stream>>>(W_ih0, W_hh0, (unsigned int*)(void*)WC08, 4096, 2048, 1024);
    k_cat2_8<<<dim3(8192),  dim3(256), 0, stream>>>(W_ih1, W_hh1, (unsigned int*)(void*)WC18, 4096, 1024, 1024);
    k_woutpad<<<dim3(40960), dim3(256), 0, stream>>>(Wout, WOUTP);
    k_bsum<<<dim3(32), dim3(256), 0, stream>>>(b_ih0, b_hh0, b_ih1, b_hh1, BS0, BS1);
    k_eys8<<<dim3(3232), dim3(256), 0, stream>>>(embed, ys_pad, (unsigned int*)(void*)EYS8);

    // pre_enc = fp8(tanh(hs @ Wenc^T + benc))
    k_gemm128<<<dim3(8, 100), dim3(256), 0, stream>>>(HS, WENC, 1024, 1024, benc, PRE8, (float*)nullptr, 0);
    k_dq0<<<dim3(128), dim3(256), 0, stream>>>(bdec, DQ);

    // ---- the scan
    SArgs sa;
    sa.pre8 = PRE8; sa.hs8 = HS8; sa.eys8 = EYS8;
    sa.wc0 = WC08;  sa.wc1 = WC18; sa.wdec = WDEC8;
    sa.dq = DQ;     sa.x0r = X0R;  sa.x1r = X1R; sa.zall = ZALL;
    sa.bdec = bdec; sa.bs0 = BS0;  sa.bs1 = BS1;
    sa.c0 = C0;     sa.c1 = C1;    sa.gp = GP;
    sa.part = PART; sa.lmaxg = LMAX; sa.lsumg = LSUM;
    sa.cntA = CNT;  sa.cnt0 = CNT + 32; sa.cnt1 = CNT + 96;
    sa.gcnt = CNT + 160; sa.gflag = CNT + 161;
    sa.hlens = hlens;
    void* kp[] = { &sa };
    hipLaunchCooperativeKernel((const void*)k_scan, dim3(256), dim3(256), kp, 0, stream);

    // ---- output projection + CE
    k_gemm128<<<dim3(40, 26), dim3(256), 0, stream>>>(ZALL, WOUTP, 2048, 5120, (const float*)nullptr,
                                                      (unsigned char*)nullptr, Y, 1);
    k_ce<<<dim3(3232), dim3(256), 0, stream>>>(Y, bout, ys_pad, out);
}